// Round 1
// baseline (245.758 us; speedup 1.0000x reference)
//
#include <hip/hip_runtime.h>
#include <hip/hip_bf16.h>

typedef signed char i8;
typedef int v4i __attribute__((ext_vector_type(4)));

#define NROWS 4096   // B*L
#define DM 1024      // d_model
#define DI 2048      // d_inner
#define LSTR 80      // LDS row stride (bytes) for i8 tiles: breaks bank-conflict pow2

// ---------------- weight |w| sum (fp64, deterministic) ----------------
__global__ __launch_bounds__(256) void k_abssum(const float* __restrict__ w, int n,
                                                double* __restrict__ partial) {
  __shared__ double sd[256];
  double acc = 0.0;
  for (int i = blockIdx.x * 256 + threadIdx.x; i < n; i += gridDim.x * 256)
    acc += (double)fabsf(w[i]);
  sd[threadIdx.x] = acc;
  __syncthreads();
  for (int s = 128; s > 0; s >>= 1) {
    if (threadIdx.x < s) sd[threadIdx.x] += sd[threadIdx.x + s];
    __syncthreads();
  }
  if (threadIdx.x == 0) partial[blockIdx.x] = sd[0];
}

__global__ void k_finalize(const double* __restrict__ partial, float* __restrict__ scales) {
  int m = threadIdx.x;
  if (m >= 5) return;
  const int off[6] = {0, 256, 272, 288, 304, 432};
  const double cnt[5] = {4194304.0, 32768.0, 32768.0, 32768.0, 2097152.0};
  double s = 0.0;
  for (int i = off[m]; i < off[m + 1]; ++i) s += partial[i];
  float mean = (float)(s / cnt[m]);
  scales[m] = fmaxf(mean, 1e-5f);
}

// ---------------- ternary weight quant ----------------
__global__ __launch_bounds__(256) void k_wquant(const float* __restrict__ w, int n,
                                                const float* __restrict__ scales, int m,
                                                i8* __restrict__ t) {
  int idx = (blockIdx.x * 256 + threadIdx.x) * 4;
  if (idx >= n) return;
  float scale = scales[m];
  float4 v = *(const float4*)(w + idx);
  char4 q;
  q.x = (i8)fminf(fmaxf(rintf(v.x / scale), -1.f), 1.f);
  q.y = (i8)fminf(fmaxf(rintf(v.y / scale), -1.f), 1.f);
  q.z = (i8)fminf(fmaxf(rintf(v.z / scale), -1.f), 1.f);
  q.w = (i8)fminf(fmaxf(rintf(v.w / scale), -1.f), 1.f);
  *(char4*)(t + idx) = q;
}

// ---------------- per-row activation quant (bit-exact vs reference) ----------------
template <int W>
__global__ __launch_bounds__(256) void k_actquant(const float* __restrict__ x,
                                                  i8* __restrict__ q, float* __restrict__ srow) {
  constexpr int E = W / 256;
  const int r = blockIdx.x, tid = threadIdx.x;
  const float* xr = x + (size_t)r * W;
  float v[E];
  float m = 0.f;
#pragma unroll
  for (int j = 0; j < E; j += 4) {
    float4 t = *(const float4*)(xr + tid * E + j);
    v[j] = t.x; v[j + 1] = t.y; v[j + 2] = t.z; v[j + 3] = t.w;
    m = fmaxf(m, fmaxf(fmaxf(fabsf(t.x), fabsf(t.y)), fmaxf(fabsf(t.z), fabsf(t.w))));
  }
  __shared__ float sm[4];
  __shared__ float sbc;
#pragma unroll
  for (int off = 32; off > 0; off >>= 1) m = fmaxf(m, __shfl_xor(m, off));
  if ((tid & 63) == 0) sm[tid >> 6] = m;
  __syncthreads();
  if (tid == 0) {
    float mm = fmaxf(fmaxf(sm[0], sm[1]), fmaxf(sm[2], sm[3]));
    float s = 127.0f / fmaxf(mm, 1e-5f);
    sbc = s;
    srow[r] = s;
  }
  __syncthreads();
  float s = sbc;
#pragma unroll
  for (int j = 0; j < E; j += 4) {
    char4 c;
    c.x = (i8)fminf(fmaxf(rintf(v[j] * s), -128.f), 127.f);
    c.y = (i8)fminf(fmaxf(rintf(v[j + 1] * s), -128.f), 127.f);
    c.z = (i8)fminf(fmaxf(rintf(v[j + 2] * s), -128.f), 127.f);
    c.w = (i8)fminf(fmaxf(rintf(v[j + 3] * s), -128.f), 127.f);
    *(char4*)(q + (size_t)r * W + tid * E + j) = c;
  }
}

// ---------------- GEMM1: xp = qx @ tinT, fused SiLU gating ----------------
// block: 64 rows x (64 gate cols + 64 value cols), K=1024
__global__ __launch_bounds__(256) void k_gemm1(const i8* __restrict__ qx, const i8* __restrict__ tin,
                                               const float* __restrict__ sx, const float* __restrict__ scales,
                                               float* __restrict__ gated) {
  __shared__ i8 As[64 * LSTR];
  __shared__ i8 Bg[64 * LSTR];
  __shared__ i8 Bv[64 * LSTR];
  __shared__ float frow[64];
  const int tid = threadIdx.x;
  const int r0 = blockIdx.x * 64;
  const int c0 = blockIdx.y * 64;
  if (tid < 64) frow[tid] = scales[0] / sx[r0 + tid];
  const int lrow = tid >> 2, lk = (tid & 3) * 16;
  const int lane = tid & 63, wv = tid >> 6;
  const int fr = lane & 15, fk = (lane >> 4) * 16;
  v4i accg[4], accv[4];
#pragma unroll
  for (int s = 0; s < 4; ++s) {
    v4i z = {0, 0, 0, 0};
    accg[s] = z; accv[s] = z;
  }
  for (int k0 = 0; k0 < 1024; k0 += 64) {
    __syncthreads();
    *(v4i*)&As[lrow * LSTR + lk] = *(const v4i*)&qx[(r0 + lrow) * 1024 + k0 + lk];
    *(v4i*)&Bg[lrow * LSTR + lk] = *(const v4i*)&tin[(c0 + lrow) * 1024 + k0 + lk];
    *(v4i*)&Bv[lrow * LSTR + lk] = *(const v4i*)&tin[(2048 + c0 + lrow) * 1024 + k0 + lk];
    __syncthreads();
    v4i a = *(const v4i*)&As[(wv * 16 + fr) * LSTR + fk];
#pragma unroll
    for (int s = 0; s < 4; ++s) {
      v4i bg = *(const v4i*)&Bg[(s * 16 + fr) * LSTR + fk];
      accg[s] = __builtin_amdgcn_mfma_i32_16x16x64_i8(a, bg, accg[s], 0, 0, 0);
      v4i bv = *(const v4i*)&Bv[(s * 16 + fr) * LSTR + fk];
      accv[s] = __builtin_amdgcn_mfma_i32_16x16x64_i8(a, bv, accv[s], 0, 0, 0);
    }
  }
#pragma unroll
  for (int s = 0; s < 4; ++s) {
#pragma unroll
    for (int rg = 0; rg < 4; ++rg) {
      int row = wv * 16 + (lane >> 4) * 4 + rg;
      int col = s * 16 + (lane & 15);
      float f = frow[row];
      float g = (float)accg[s][rg] * f;
      float v = (float)accv[s][rg] * f;
      float sg = 1.0f / (1.0f + expf(-g));
      gated[(r0 + row) * 2048 + c0 + col] = g * sg * v;
    }
  }
}

// ---------------- causal depthwise conv1d ----------------
__global__ __launch_bounds__(256) void k_conv(const float* __restrict__ g, const float* __restrict__ cw,
                                              const float* __restrict__ cb, float* __restrict__ xo) {
  int idx = blockIdx.x * 256 + threadIdx.x;
  int d = idx & 2047;
  int r = idx >> 11;
  int l = r & 2047;
  float acc = cb[d];
#pragma unroll
  for (int k = 0; k < 4; ++k) {
    int lo = l + k - 3;
    if (lo >= 0) acc = fmaf(cw[d * 4 + k], g[idx + (k - 3) * 2048], acc);
  }
  xo[idx] = acc;
}

// ---------------- GEMM2: [4096 x 2048] @ [48 x 2048]^T -> delta|B|C ----------------
__global__ __launch_bounds__(256) void k_gemm2(const i8* __restrict__ q2, const i8* __restrict__ t2,
                                               const float* __restrict__ s2, const float* __restrict__ scales,
                                               const float* __restrict__ dbias, float* __restrict__ mat) {
  __shared__ i8 As[64 * LSTR];
  __shared__ i8 Bs[48 * LSTR];
  __shared__ float frow[64];
  const int tid = threadIdx.x;
  const int r0 = blockIdx.x * 64;
  if (tid < 64) frow[tid] = 1.0f / s2[r0 + tid];
  const int lrow = tid >> 2, lk = (tid & 3) * 16;
  const int lane = tid & 63, wv = tid >> 6;
  const int fr = lane & 15, fk = (lane >> 4) * 16;
  v4i acc[3];
#pragma unroll
  for (int s = 0; s < 3; ++s) { v4i z = {0, 0, 0, 0}; acc[s] = z; }
  for (int k0 = 0; k0 < 2048; k0 += 64) {
    __syncthreads();
    *(v4i*)&As[lrow * LSTR + lk] = *(const v4i*)&q2[(r0 + lrow) * 2048 + k0 + lk];
    if (tid < 192)
      *(v4i*)&Bs[(tid >> 2) * LSTR + (tid & 3) * 16] = *(const v4i*)&t2[(tid >> 2) * 2048 + k0 + (tid & 3) * 16];
    __syncthreads();
    v4i a = *(const v4i*)&As[(wv * 16 + fr) * LSTR + fk];
#pragma unroll
    for (int s = 0; s < 3; ++s) {
      v4i b = *(const v4i*)&Bs[(s * 16 + fr) * LSTR + fk];
      acc[s] = __builtin_amdgcn_mfma_i32_16x16x64_i8(a, b, acc[s], 0, 0, 0);
    }
  }
#pragma unroll
  for (int s = 0; s < 3; ++s) {
    float scl = scales[1 + s];
#pragma unroll
    for (int rg = 0; rg < 4; ++rg) {
      int row = wv * 16 + (lane >> 4) * 4 + rg;
      int col = s * 16 + (lane & 15);
      float v = (float)acc[s][rg] * scl * frow[row];
      if (s == 0) v += dbias[lane & 15];
      mat[(r0 + row) * 48 + col] = v;
    }
  }
}

// ---------------- transform: A_d, delta*B, C -> [b*16+n][t] ----------------
__global__ __launch_bounds__(256) void k_xform(const float* __restrict__ mat, const float* __restrict__ logA,
                                               float* __restrict__ At, float* __restrict__ dBt,
                                               float* __restrict__ Ct) {
  int idx = blockIdx.x * 256 + threadIdx.x;  // 4096*16
  int r = idx >> 4, n = idx & 15;
  int b = r >> 11, l = r & 2047;
  float d = mat[r * 48 + n];
  float Bv = mat[r * 48 + 16 + n];
  float Cv = mat[r * 48 + 32 + n];
  int o = ((b * 16 + n) << 11) | l;
  At[o] = expf(d * logA[n]);
  dBt[o] = d * Bv;
  Ct[o] = Cv;
}

// ---------------- parallel scan over time per (b,n) ----------------
__global__ __launch_bounds__(256) void k_scan(const float* __restrict__ At, const float* __restrict__ dBt,
                                              const float* __restrict__ Ct, float* __restrict__ ch) {
  const int i = threadIdx.x;
  const int base = blockIdx.x << 11;
  float a[8], db[8], c[8];
  {
    const float4* p = (const float4*)(At + base + i * 8);
    float4 t0 = p[0], t1 = p[1];
    a[0]=t0.x; a[1]=t0.y; a[2]=t0.z; a[3]=t0.w; a[4]=t1.x; a[5]=t1.y; a[6]=t1.z; a[7]=t1.w;
  }
  {
    const float4* p = (const float4*)(dBt + base + i * 8);
    float4 t0 = p[0], t1 = p[1];
    db[0]=t0.x; db[1]=t0.y; db[2]=t0.z; db[3]=t0.w; db[4]=t1.x; db[5]=t1.y; db[6]=t1.z; db[7]=t1.w;
  }
  {
    const float4* p = (const float4*)(Ct + base + i * 8);
    float4 t0 = p[0], t1 = p[1];
    c[0]=t0.x; c[1]=t0.y; c[2]=t0.z; c[3]=t0.w; c[4]=t1.x; c[5]=t1.y; c[6]=t1.z; c[7]=t1.w;
  }
  float Ac = 1.f, Bc = 0.f;
#pragma unroll
  for (int j = 0; j < 8; ++j) { Bc = a[j] * Bc + db[j]; Ac *= a[j]; }
  __shared__ float sA[256], sB[256];
  sA[i] = Ac; sB[i] = Bc;
  __syncthreads();
  for (int off = 1; off < 256; off <<= 1) {
    float pA = 1.f, pB = 0.f;
    if (i >= off) { pA = sA[i - off]; pB = sB[i - off]; }
    __syncthreads();
    Bc = Ac * pB + Bc;   // compose(earlier, self)
    Ac = Ac * pA;
    sA[i] = Ac; sB[i] = Bc;
    __syncthreads();
  }
  float h = (i > 0) ? sB[i - 1] : 0.f;
  float o[8];
#pragma unroll
  for (int j = 0; j < 8; ++j) { h = a[j] * h + db[j]; o[j] = c[j] * h; }
  float4* po = (float4*)(ch + base + i * 8);
  po[0] = make_float4(o[0], o[1], o[2], o[3]);
  po[1] = make_float4(o[4], o[5], o[6], o[7]);
}

// ---------------- y_inner = x_input*(sigmoid(sig)+D), fused act-quant ----------------
__global__ __launch_bounds__(256) void k_yq(const float* __restrict__ xin, const float* __restrict__ ch,
                                            const float* __restrict__ Dp, i8* __restrict__ q,
                                            float* __restrict__ srow) {
  const int r = blockIdx.x, tid = threadIdx.x;
  const int b = r >> 11, l = r & 2047;
  __shared__ float s16[16];
  __shared__ float sm[4];
  __shared__ float sbc[2];
  if (tid < 16) s16[tid] = ch[((b * 16 + tid) << 11) + l];
  __syncthreads();
  if (tid == 0) {
    float s = 0.f;
    for (int n = 0; n < 16; ++n) s += s16[n];
    sbc[0] = 1.0f / (1.0f + expf(-s));
  }
  __syncthreads();
  float sg = sbc[0];
  const float* xr = xin + (size_t)r * 2048;
  float y[8];
  float m = 0.f;
#pragma unroll
  for (int j = 0; j < 8; j += 4) {
    float4 xv = *(const float4*)(xr + tid * 8 + j);
    float4 dv = *(const float4*)(Dp + tid * 8 + j);
    y[j] = xv.x * (sg + dv.x);
    y[j + 1] = xv.y * (sg + dv.y);
    y[j + 2] = xv.z * (sg + dv.z);
    y[j + 3] = xv.w * (sg + dv.w);
    m = fmaxf(m, fmaxf(fmaxf(fabsf(y[j]), fabsf(y[j + 1])), fmaxf(fabsf(y[j + 2]), fabsf(y[j + 3]))));
  }
#pragma unroll
  for (int off = 32; off > 0; off >>= 1) m = fmaxf(m, __shfl_xor(m, off));
  if ((tid & 63) == 0) sm[tid >> 6] = m;
  __syncthreads();
  if (tid == 0) {
    float mm = fmaxf(fmaxf(sm[0], sm[1]), fmaxf(sm[2], sm[3]));
    float s = 127.0f / fmaxf(mm, 1e-5f);
    sbc[1] = s;
    srow[r] = s;
  }
  __syncthreads();
  float s = sbc[1];
#pragma unroll
  for (int j = 0; j < 8; j += 4) {
    char4 cq;
    cq.x = (i8)fminf(fmaxf(rintf(y[j] * s), -128.f), 127.f);
    cq.y = (i8)fminf(fmaxf(rintf(y[j + 1] * s), -128.f), 127.f);
    cq.z = (i8)fminf(fmaxf(rintf(y[j + 2] * s), -128.f), 127.f);
    cq.w = (i8)fminf(fmaxf(rintf(y[j + 3] * s), -128.f), 127.f);
    *(char4*)(q + (size_t)r * 2048 + tid * 8 + j) = cq;
  }
}

// ---------------- GEMM3: out = q3 @ toutT ----------------
__global__ __launch_bounds__(256) void k_gemm3(const i8* __restrict__ q3, const i8* __restrict__ tout,
                                               const float* __restrict__ s3, const float* __restrict__ scales,
                                               float* __restrict__ out) {
  __shared__ i8 As[64 * LSTR];
  __shared__ i8 Bs[64 * LSTR];
  __shared__ float frow[64];
  const int tid = threadIdx.x;
  const int r0 = blockIdx.x * 64;
  const int c0 = blockIdx.y * 64;
  if (tid < 64) frow[tid] = scales[4] / s3[r0 + tid];
  const int lrow = tid >> 2, lk = (tid & 3) * 16;
  const int lane = tid & 63, wv = tid >> 6;
  const int fr = lane & 15, fk = (lane >> 4) * 16;
  v4i acc[4];
#pragma unroll
  for (int s = 0; s < 4; ++s) { v4i z = {0, 0, 0, 0}; acc[s] = z; }
  for (int k0 = 0; k0 < 2048; k0 += 64) {
    __syncthreads();
    *(v4i*)&As[lrow * LSTR + lk] = *(const v4i*)&q3[(r0 + lrow) * 2048 + k0 + lk];
    *(v4i*)&Bs[lrow * LSTR + lk] = *(const v4i*)&tout[(c0 + lrow) * 2048 + k0 + lk];
    __syncthreads();
    v4i a = *(const v4i*)&As[(wv * 16 + fr) * LSTR + fk];
#pragma unroll
    for (int s = 0; s < 4; ++s) {
      v4i b = *(const v4i*)&Bs[(s * 16 + fr) * LSTR + fk];
      acc[s] = __builtin_amdgcn_mfma_i32_16x16x64_i8(a, b, acc[s], 0, 0, 0);
    }
  }
#pragma unroll
  for (int s = 0; s < 4; ++s) {
#pragma unroll
    for (int rg = 0; rg < 4; ++rg) {
      int row = wv * 16 + (lane >> 4) * 4 + rg;
      int col = s * 16 + (lane & 15);
      out[(r0 + row) * 1024 + c0 + col] = (float)acc[s][rg] * frow[row];
    }
  }
}

extern "C" void kernel_launch(void* const* d_in, const int* in_sizes, int n_in,
                              void* d_out, int out_size, void* d_ws, size_t ws_size,
                              hipStream_t stream) {
  const float* x     = (const float*)d_in[0];
  const float* win   = (const float*)d_in[1];
  const float* cw    = (const float*)d_in[2];
  const float* cb    = (const float*)d_in[3];
  const float* dw    = (const float*)d_in[4];
  const float* dbias = (const float*)d_in[5];
  const float* bw    = (const float*)d_in[6];
  const float* cmw   = (const float*)d_in[7];
  const float* ow    = (const float*)d_in[8];
  const float* Dp    = (const float*)d_in[9];
  const float* logA  = (const float*)d_in[10];
  float* out = (float*)d_out;

  char* p = (char*)d_ws;
  float* gated = (float*)p;   p += (size_t)NROWS * DI * 4;   // 32MB
  float* xin   = (float*)p;   p += (size_t)NROWS * DI * 4;   // 32MB
  i8* qx   = (i8*)p;          p += (size_t)NROWS * DM;       // 4MB
  i8* tin  = (i8*)p;          p += (size_t)2 * DI * DM;      // 4MB
  i8* tout = (i8*)p;          p += (size_t)DM * DI;          // 2MB
  i8* t2   = (i8*)p;          p += (size_t)48 * DI;
  i8* q2   = (i8*)p;          p += (size_t)NROWS * DI;       // 8MB
  i8* q3   = (i8*)p;          p += (size_t)NROWS * DI;       // 8MB
  float* mat = (float*)p;     p += (size_t)NROWS * 48 * 4;
  float* At  = (float*)p;     p += (size_t)32 * 2048 * 4;
  float* dBt = (float*)p;     p += (size_t)32 * 2048 * 4;
  float* Ct  = (float*)p;     p += (size_t)32 * 2048 * 4;
  float* chb = (float*)p;     p += (size_t)32 * 2048 * 4;
  float* sx  = (float*)p;     p += (size_t)NROWS * 4;
  float* s2  = (float*)p;     p += (size_t)NROWS * 4;
  float* s3  = (float*)p;     p += (size_t)NROWS * 4;
  float* scales = (float*)p;  p += 256;
  double* partial = (double*)p;

  // weight scales (fp64 deterministic two-pass)
  k_abssum<<<256, 256, 0, stream>>>(win, 4194304, partial + 0);
  k_abssum<<<16, 256, 0, stream>>>(dw, 32768, partial + 256);
  k_abssum<<<16, 256, 0, stream>>>(bw, 32768, partial + 272);
  k_abssum<<<16, 256, 0, stream>>>(cmw, 32768, partial + 288);
  k_abssum<<<128, 256, 0, stream>>>(ow, 2097152, partial + 304);
  k_finalize<<<1, 64, 0, stream>>>(partial, scales);

  // ternary weight quantization
  k_wquant<<<4096, 256, 0, stream>>>(win, 4194304, scales, 0, tin);
  k_wquant<<<32, 256, 0, stream>>>(dw, 32768, scales, 1, t2);
  k_wquant<<<32, 256, 0, stream>>>(bw, 32768, scales, 2, t2 + 16 * 2048);
  k_wquant<<<32, 256, 0, stream>>>(cmw, 32768, scales, 3, t2 + 32 * 2048);
  k_wquant<<<2048, 256, 0, stream>>>(ow, 2097152, scales, 4, tout);

  // pipeline
  k_actquant<1024><<<4096, 256, 0, stream>>>(x, qx, sx);
  k_gemm1<<<dim3(64, 32), 256, 0, stream>>>(qx, tin, sx, scales, gated);
  k_conv<<<32768, 256, 0, stream>>>(gated, cw, cb, xin);
  k_actquant<2048><<<4096, 256, 0, stream>>>(xin, q2, s2);
  k_gemm2<<<64, 256, 0, stream>>>(q2, t2, s2, scales, dbias, mat);
  k_xform<<<256, 256, 0, stream>>>(mat, logA, At, dBt, Ct);
  k_scan<<<32, 256, 0, stream>>>(At, dBt, Ct, chb);
  k_yq<<<4096, 256, 0, stream>>>(xin, chb, Dp, q3, s3);
  k_gemm3<<<dim3(64, 16), 256, 0, stream>>>(q3, tout, s3, scales, out);
}

// Round 2
// 180.357 us; speedup vs baseline: 1.3626x; 1.3626x over previous
//
#include <hip/hip_runtime.h>
#include <hip/hip_bf16.h>

typedef signed char i8;
typedef int v4i __attribute__((ext_vector_type(4)));

#define LSTR 80  // LDS row stride (bytes) for gemm2 staging

__device__ __forceinline__ void gld16(const void* g, void* l) {
  __builtin_amdgcn_global_load_lds(
      (const __attribute__((address_space(1))) unsigned int*)g,
      (__attribute__((address_space(3))) unsigned int*)l, 16, 0, 0);
}

// ---------------- merged |w| abs-sum (fp64, deterministic layout) ----------------
__global__ __launch_bounds__(256) void k_abssum_all(const float* __restrict__ w0, const float* __restrict__ w1,
                                                    const float* __restrict__ w2, const float* __restrict__ w3,
                                                    const float* __restrict__ w4, double* __restrict__ partial) {
  int b = blockIdx.x;
  const float* w; int n, nb, bg;
  if (b < 256)      { w = w0; n = 4194304; nb = 256; bg = b; }
  else if (b < 272) { w = w1; n = 32768;   nb = 16;  bg = b - 256; }
  else if (b < 288) { w = w2; n = 32768;   nb = 16;  bg = b - 272; }
  else if (b < 304) { w = w3; n = 32768;   nb = 16;  bg = b - 288; }
  else              { w = w4; n = 2097152; nb = 128; bg = b - 304; }
  __shared__ double sd[256];
  double acc = 0.0;
  for (int i = bg * 256 + threadIdx.x; i < n; i += nb * 256) acc += (double)fabsf(w[i]);
  sd[threadIdx.x] = acc;
  __syncthreads();
  for (int s = 128; s > 0; s >>= 1) {
    if (threadIdx.x < s) sd[threadIdx.x] += sd[threadIdx.x + s];
    __syncthreads();
  }
  if (threadIdx.x == 0) partial[b] = sd[0];
}

__global__ void k_finalize(const double* __restrict__ partial, float* __restrict__ scales) {
  int m = threadIdx.x;
  if (m >= 5) return;
  const int off[6] = {0, 256, 272, 288, 304, 432};
  const double cnt[5] = {4194304.0, 32768.0, 32768.0, 32768.0, 2097152.0};
  double s = 0.0;
  for (int i = off[m]; i < off[m + 1]; ++i) s += partial[i];
  scales[m] = fmaxf((float)(s / cnt[m]), 1e-5f);
}

// ---------------- merged ternary weight quant ----------------
__global__ __launch_bounds__(256) void k_wquant_all(const float* __restrict__ w0, const float* __restrict__ w1,
                                                    const float* __restrict__ w2, const float* __restrict__ w3,
                                                    const float* __restrict__ w4, const float* __restrict__ scales,
                                                    i8* __restrict__ tin, i8* __restrict__ t2, i8* __restrict__ tout) {
  int b = blockIdx.x;
  const float* w; i8* t; int m, n;
  if (b < 4096)      { w = w0; t = tin;          m = 0; n = 4194304; }
  else if (b < 4128) { w = w1; t = t2;           m = 1; n = 32768; b -= 4096; }
  else if (b < 4160) { w = w2; t = t2 + 32768;   m = 2; n = 32768; b -= 4128; }
  else if (b < 4192) { w = w3; t = t2 + 65536;   m = 3; n = 32768; b -= 4160; }
  else               { w = w4; t = tout;         m = 4; n = 2097152; b -= 4192; }
  int idx = (b * 256 + threadIdx.x) * 4;
  if (idx >= n) return;
  float scale = scales[m];
  float4 v = *(const float4*)(w + idx);
  char4 q;
  q.x = (i8)fminf(fmaxf(rintf(v.x / scale), -1.f), 1.f);
  q.y = (i8)fminf(fmaxf(rintf(v.y / scale), -1.f), 1.f);
  q.z = (i8)fminf(fmaxf(rintf(v.z / scale), -1.f), 1.f);
  q.w = (i8)fminf(fmaxf(rintf(v.w / scale), -1.f), 1.f);
  *(char4*)(t + idx) = q;
}

// ---------------- per-row activation quant (bit-exact vs reference) ----------------
template <int W>
__global__ __launch_bounds__(256) void k_actquant(const float* __restrict__ x,
                                                  i8* __restrict__ q, float* __restrict__ srow) {
  constexpr int E = W / 256;
  const int r = blockIdx.x, tid = threadIdx.x;
  const float* xr = x + (size_t)r * W;
  float v[E];
  float m = 0.f;
#pragma unroll
  for (int j = 0; j < E; j += 4) {
    float4 t = *(const float4*)(xr + tid * E + j);
    v[j] = t.x; v[j + 1] = t.y; v[j + 2] = t.z; v[j + 3] = t.w;
    m = fmaxf(m, fmaxf(fmaxf(fabsf(t.x), fabsf(t.y)), fmaxf(fabsf(t.z), fabsf(t.w))));
  }
  __shared__ float sm[4];
  __shared__ float sbc;
#pragma unroll
  for (int off = 32; off > 0; off >>= 1) m = fmaxf(m, __shfl_xor(m, off));
  if ((tid & 63) == 0) sm[tid >> 6] = m;
  __syncthreads();
  if (tid == 0) {
    float mm = fmaxf(fmaxf(sm[0], sm[1]), fmaxf(sm[2], sm[3]));
    float s = 127.0f / fmaxf(mm, 1e-5f);
    sbc = s;
    srow[r] = s;
  }
  __syncthreads();
  float s = sbc;
#pragma unroll
  for (int j = 0; j < E; j += 4) {
    char4 c;
    c.x = (i8)fminf(fmaxf(rintf(v[j] * s), -128.f), 127.f);
    c.y = (i8)fminf(fmaxf(rintf(v[j + 1] * s), -128.f), 127.f);
    c.z = (i8)fminf(fmaxf(rintf(v[j + 2] * s), -128.f), 127.f);
    c.w = (i8)fminf(fmaxf(rintf(v[j + 3] * s), -128.f), 127.f);
    *(char4*)(q + (size_t)r * W + tid * E + j) = c;
  }
}

// ---------------- GEMM1: 128x128 tile, BK=128, global_load_lds + XOR swizzle ----------------
// block computes gated[r0:r0+128][c0:c0+128] = silu(gate)*value, K=1024
__global__ __launch_bounds__(256) void k_gemm1(const i8* __restrict__ qx, const i8* __restrict__ tin,
                                               const float* __restrict__ sx, const float* __restrict__ scales,
                                               float* __restrict__ gated) {
  __shared__ i8 As[16384], Bg[16384], Bv[16384];
  __shared__ float frow[128];
  const int tid = threadIdx.x;
  const int r0 = blockIdx.x * 128, c0 = blockIdx.y * 128;
  if (tid < 128) frow[tid] = scales[0] / sx[r0 + tid];
  const int lane = tid & 63, wv = tid >> 6;
  const int wr = wv >> 1, wc = wv & 1;
  const int lo = lane & 15, hi = lane >> 4;
  const int sr = tid >> 3;   // staged row (per i: r = i*32 + sr)
  const int sp = tid & 7;    // physical 16B chunk within 128B row
  v4i accg[4][4], accv[4][4];
#pragma unroll
  for (int m = 0; m < 4; ++m)
#pragma unroll
    for (int n = 0; n < 4; ++n) {
      accg[m][n] = (v4i){0, 0, 0, 0};
      accv[m][n] = (v4i){0, 0, 0, 0};
    }
  for (int kt = 0; kt < 8; ++kt) {
    const int kb = kt * 128;
    __syncthreads();
#pragma unroll
    for (int i = 0; i < 4; ++i) {
      int r = i * 32 + sr;
      int src = kb + ((sp ^ (r & 7)) << 4);  // inverse-swizzled global source
      int lds = i * 4096 + wv * 1024;        // wave-uniform linear dest
      gld16(qx + (size_t)(r0 + r) * 1024 + src, As + lds);
      gld16(tin + (size_t)(c0 + r) * 1024 + src, Bg + lds);
      gld16(tin + (size_t)(2048 + c0 + r) * 1024 + src, Bv + lds);
    }
    __syncthreads();
#pragma unroll
    for (int kh = 0; kh < 2; ++kh) {
      v4i a[4];
#pragma unroll
      for (int m = 0; m < 4; ++m) {
        int rr = wr * 64 + m * 16 + lo;
        int c = kh * 4 + hi;
        a[m] = *(const v4i*)&As[rr * 128 + ((c ^ (rr & 7)) << 4)];
      }
#pragma unroll
      for (int n = 0; n < 4; ++n) {
        int cc = wc * 64 + n * 16 + lo;
        int c = kh * 4 + hi;
        int off = cc * 128 + ((c ^ (cc & 7)) << 4);
        v4i bg = *(const v4i*)&Bg[off];
        v4i bv = *(const v4i*)&Bv[off];
#pragma unroll
        for (int m = 0; m < 4; ++m) {
          accg[m][n] = __builtin_amdgcn_mfma_i32_16x16x64_i8(a[m], bg, accg[m][n], 0, 0, 0);
          accv[m][n] = __builtin_amdgcn_mfma_i32_16x16x64_i8(a[m], bv, accv[m][n], 0, 0, 0);
        }
      }
    }
  }
#pragma unroll
  for (int m = 0; m < 4; ++m)
#pragma unroll
    for (int n = 0; n < 4; ++n)
#pragma unroll
      for (int rg = 0; rg < 4; ++rg) {
        int row = wr * 64 + m * 16 + hi * 4 + rg;
        int col = wc * 64 + n * 16 + lo;
        float f = frow[row];
        float g = (float)accg[m][n][rg] * f;
        float v = (float)accv[m][n][rg] * f;
        float sg = 1.0f / (1.0f + expf(-g));
        gated[(size_t)(r0 + row) * 2048 + c0 + col] = g * sg * v;
      }
}

// ---------------- fused causal depthwise conv + act-quant ----------------
__global__ __launch_bounds__(256) void k_convq(const float* __restrict__ g, const float* __restrict__ cw,
                                               const float* __restrict__ cb, float* __restrict__ xo,
                                               i8* __restrict__ q, float* __restrict__ srow) {
  const int r = blockIdx.x, tid = threadIdx.x;
  const int l = r & 2047;
  const int ch = tid * 8;
  float acc[8];
  {
    float4 b0 = *(const float4*)(cb + ch), b1 = *(const float4*)(cb + ch + 4);
    acc[0] = b0.x; acc[1] = b0.y; acc[2] = b0.z; acc[3] = b0.w;
    acc[4] = b1.x; acc[5] = b1.y; acc[6] = b1.z; acc[7] = b1.w;
  }
  float wt[8][4];
#pragma unroll
  for (int j = 0; j < 8; ++j) {
    float4 w = *(const float4*)(cw + (ch + j) * 4);
    wt[j][0] = w.x; wt[j][1] = w.y; wt[j][2] = w.z; wt[j][3] = w.w;
  }
  const float* gr = g + (size_t)r * 2048 + ch;
#pragma unroll
  for (int k = 0; k < 4; ++k) {
    int dl = k - 3;
    if (l + dl >= 0) {  // block-uniform branch
      float4 g0 = *(const float4*)(gr + (ptrdiff_t)dl * 2048);
      float4 g1 = *(const float4*)(gr + (ptrdiff_t)dl * 2048 + 4);
      acc[0] = fmaf(wt[0][k], g0.x, acc[0]);
      acc[1] = fmaf(wt[1][k], g0.y, acc[1]);
      acc[2] = fmaf(wt[2][k], g0.z, acc[2]);
      acc[3] = fmaf(wt[3][k], g0.w, acc[3]);
      acc[4] = fmaf(wt[4][k], g1.x, acc[4]);
      acc[5] = fmaf(wt[5][k], g1.y, acc[5]);
      acc[6] = fmaf(wt[6][k], g1.z, acc[6]);
      acc[7] = fmaf(wt[7][k], g1.w, acc[7]);
    }
  }
  *(float4*)(xo + (size_t)r * 2048 + ch) = make_float4(acc[0], acc[1], acc[2], acc[3]);
  *(float4*)(xo + (size_t)r * 2048 + ch + 4) = make_float4(acc[4], acc[5], acc[6], acc[7]);
  float m = 0.f;
#pragma unroll
  for (int j = 0; j < 8; ++j) m = fmaxf(m, fabsf(acc[j]));
  __shared__ float sm[4];
  __shared__ float sbc;
#pragma unroll
  for (int off = 32; off > 0; off >>= 1) m = fmaxf(m, __shfl_xor(m, off));
  if ((tid & 63) == 0) sm[tid >> 6] = m;
  __syncthreads();
  if (tid == 0) {
    float mm = fmaxf(fmaxf(sm[0], sm[1]), fmaxf(sm[2], sm[3]));
    float s = 127.0f / fmaxf(mm, 1e-5f);
    sbc = s;
    srow[r] = s;
  }
  __syncthreads();
  float s = sbc;
  char4 c0q, c1q;
  c0q.x = (i8)fminf(fmaxf(rintf(acc[0] * s), -128.f), 127.f);
  c0q.y = (i8)fminf(fmaxf(rintf(acc[1] * s), -128.f), 127.f);
  c0q.z = (i8)fminf(fmaxf(rintf(acc[2] * s), -128.f), 127.f);
  c0q.w = (i8)fminf(fmaxf(rintf(acc[3] * s), -128.f), 127.f);
  c1q.x = (i8)fminf(fmaxf(rintf(acc[4] * s), -128.f), 127.f);
  c1q.y = (i8)fminf(fmaxf(rintf(acc[5] * s), -128.f), 127.f);
  c1q.z = (i8)fminf(fmaxf(rintf(acc[6] * s), -128.f), 127.f);
  c1q.w = (i8)fminf(fmaxf(rintf(acc[7] * s), -128.f), 127.f);
  *(char4*)(q + (size_t)r * 2048 + ch) = c0q;
  *(char4*)(q + (size_t)r * 2048 + ch + 4) = c1q;
}

// ---------------- GEMM2: K-split i32 partials, [4096 x 1024y] @ [48 x K]^T ----------------
__global__ __launch_bounds__(256) void k_gemm2(const i8* __restrict__ q2, const i8* __restrict__ t2,
                                               int* __restrict__ ipart) {
  __shared__ i8 As[64 * LSTR];
  __shared__ i8 Bs[48 * LSTR];
  const int tid = threadIdx.x;
  const int r0 = blockIdx.x * 64;
  const int kb = blockIdx.y * 1024;
  const int lrow = tid >> 2, lk = (tid & 3) * 16;
  const int lane = tid & 63, wv = tid >> 6;
  const int fr = lane & 15, fk = (lane >> 4) * 16;
  v4i acc[3];
#pragma unroll
  for (int s = 0; s < 3; ++s) acc[s] = (v4i){0, 0, 0, 0};
  for (int ks = 0; ks < 16; ++ks) {
    const int k0 = kb + ks * 64;
    __syncthreads();
    *(v4i*)&As[lrow * LSTR + lk] = *(const v4i*)&q2[(size_t)(r0 + lrow) * 2048 + k0 + lk];
    if (tid < 192)
      *(v4i*)&Bs[(tid >> 2) * LSTR + (tid & 3) * 16] = *(const v4i*)&t2[(size_t)(tid >> 2) * 2048 + k0 + (tid & 3) * 16];
    __syncthreads();
    v4i a = *(const v4i*)&As[(wv * 16 + fr) * LSTR + fk];
#pragma unroll
    for (int s = 0; s < 3; ++s) {
      v4i b = *(const v4i*)&Bs[(s * 16 + fr) * LSTR + fk];
      acc[s] = __builtin_amdgcn_mfma_i32_16x16x64_i8(a, b, acc[s], 0, 0, 0);
    }
  }
#pragma unroll
  for (int s = 0; s < 3; ++s)
#pragma unroll
    for (int rg = 0; rg < 4; ++rg) {
      int row = wv * 16 + (lane >> 4) * 4 + rg;
      int col = s * 16 + (lane & 15);
      ipart[(size_t)blockIdx.y * 196608 + (size_t)(r0 + row) * 48 + col] = acc[s][rg];
    }
}

// ---------------- combine partials, dequant, build A_d / delta*B / C transposed ----------------
__global__ __launch_bounds__(256) void k_xform(const int* __restrict__ ip, const float* __restrict__ s2,
                                               const float* __restrict__ scales, const float* __restrict__ dbias,
                                               const float* __restrict__ logA, float* __restrict__ At,
                                               float* __restrict__ dBt, float* __restrict__ Ct) {
  int idx = blockIdx.x * 256 + threadIdx.x;  // 4096*16
  int r = idx >> 4, n = idx & 15;
  int b = r >> 11, l = r & 2047;
  float fr = 1.0f / s2[r];
  int base = r * 48;
  float dd = (float)(ip[base + n] + ip[196608 + base + n]) * (scales[1] * fr) + dbias[n];
  float Bv = (float)(ip[base + 16 + n] + ip[196608 + base + 16 + n]) * (scales[2] * fr);
  float Cv = (float)(ip[base + 32 + n] + ip[196608 + base + 32 + n]) * (scales[3] * fr);
  int o = ((b * 16 + n) << 11) | l;
  At[o] = expf(dd * logA[n]);
  dBt[o] = dd * Bv;
  Ct[o] = Cv;
}

// ---------------- parallel scan over time per (b,n) ----------------
__global__ __launch_bounds__(256) void k_scan(const float* __restrict__ At, const float* __restrict__ dBt,
                                              const float* __restrict__ Ct, float* __restrict__ ch) {
  const int i = threadIdx.x;
  const int base = blockIdx.x << 11;
  float a[8], db[8], c[8];
  {
    const float4* p = (const float4*)(At + base + i * 8);
    float4 t0 = p[0], t1 = p[1];
    a[0]=t0.x; a[1]=t0.y; a[2]=t0.z; a[3]=t0.w; a[4]=t1.x; a[5]=t1.y; a[6]=t1.z; a[7]=t1.w;
  }
  {
    const float4* p = (const float4*)(dBt + base + i * 8);
    float4 t0 = p[0], t1 = p[1];
    db[0]=t0.x; db[1]=t0.y; db[2]=t0.z; db[3]=t0.w; db[4]=t1.x; db[5]=t1.y; db[6]=t1.z; db[7]=t1.w;
  }
  {
    const float4* p = (const float4*)(Ct + base + i * 8);
    float4 t0 = p[0], t1 = p[1];
    c[0]=t0.x; c[1]=t0.y; c[2]=t0.z; c[3]=t0.w; c[4]=t1.x; c[5]=t1.y; c[6]=t1.z; c[7]=t1.w;
  }
  float Ac = 1.f, Bc = 0.f;
#pragma unroll
  for (int j = 0; j < 8; ++j) { Bc = a[j] * Bc + db[j]; Ac *= a[j]; }
  __shared__ float sA[256], sB[256];
  sA[i] = Ac; sB[i] = Bc;
  __syncthreads();
  for (int off = 1; off < 256; off <<= 1) {
    float pA = 1.f, pB = 0.f;
    if (i >= off) { pA = sA[i - off]; pB = sB[i - off]; }
    __syncthreads();
    Bc = Ac * pB + Bc;
    Ac = Ac * pA;
    sA[i] = Ac; sB[i] = Bc;
    __syncthreads();
  }
  float h = (i > 0) ? sB[i - 1] : 0.f;
  float o[8];
#pragma unroll
  for (int j = 0; j < 8; ++j) { h = a[j] * h + db[j]; o[j] = c[j] * h; }
  float4* po = (float4*)(ch + base + i * 8);
  po[0] = make_float4(o[0], o[1], o[2], o[3]);
  po[1] = make_float4(o[4], o[5], o[6], o[7]);
}

// ---------------- y_inner = x_input*(sigmoid(sig)+D), fused act-quant ----------------
__global__ __launch_bounds__(256) void k_yq(const float* __restrict__ xin, const float* __restrict__ ch,
                                            const float* __restrict__ Dp, i8* __restrict__ q,
                                            float* __restrict__ srow) {
  const int r = blockIdx.x, tid = threadIdx.x;
  const int b = r >> 11, l = r & 2047;
  __shared__ float s16[16];
  __shared__ float sm[4];
  __shared__ float sbc[2];
  if (tid < 16) s16[tid] = ch[((b * 16 + tid) << 11) + l];
  __syncthreads();
  if (tid == 0) {
    float s = 0.f;
    for (int n = 0; n < 16; ++n) s += s16[n];
    sbc[0] = 1.0f / (1.0f + expf(-s));
  }
  __syncthreads();
  float sg = sbc[0];
  const float* xr = xin + (size_t)r * 2048;
  float y[8];
  float m = 0.f;
#pragma unroll
  for (int j = 0; j < 8; j += 4) {
    float4 xv = *(const float4*)(xr + tid * 8 + j);
    float4 dv = *(const float4*)(Dp + tid * 8 + j);
    y[j] = xv.x * (sg + dv.x);
    y[j + 1] = xv.y * (sg + dv.y);
    y[j + 2] = xv.z * (sg + dv.z);
    y[j + 3] = xv.w * (sg + dv.w);
    m = fmaxf(m, fmaxf(fmaxf(fabsf(y[j]), fabsf(y[j + 1])), fmaxf(fabsf(y[j + 2]), fabsf(y[j + 3]))));
  }
#pragma unroll
  for (int off = 32; off > 0; off >>= 1) m = fmaxf(m, __shfl_xor(m, off));
  if ((tid & 63) == 0) sm[tid >> 6] = m;
  __syncthreads();
  if (tid == 0) {
    float mm = fmaxf(fmaxf(sm[0], sm[1]), fmaxf(sm[2], sm[3]));
    float s = 127.0f / fmaxf(mm, 1e-5f);
    sbc[1] = s;
    srow[r] = s;
  }
  __syncthreads();
  float s = sbc[1];
#pragma unroll
  for (int j = 0; j < 8; j += 4) {
    char4 cq;
    cq.x = (i8)fminf(fmaxf(rintf(y[j] * s), -128.f), 127.f);
    cq.y = (i8)fminf(fmaxf(rintf(y[j + 1] * s), -128.f), 127.f);
    cq.z = (i8)fminf(fmaxf(rintf(y[j + 2] * s), -128.f), 127.f);
    cq.w = (i8)fminf(fmaxf(rintf(y[j + 3] * s), -128.f), 127.f);
    *(char4*)(q + (size_t)r * 2048 + tid * 8 + j) = cq;
  }
}

// ---------------- GEMM3: 128x128 tile, BK=128, K=2048 ----------------
__global__ __launch_bounds__(256) void k_gemm3(const i8* __restrict__ q3, const i8* __restrict__ tout,
                                               const float* __restrict__ s3, const float* __restrict__ scales,
                                               float* __restrict__ out) {
  __shared__ i8 As[16384], Bs[16384];
  __shared__ float frow[128];
  const int tid = threadIdx.x;
  const int r0 = blockIdx.x * 128, c0 = blockIdx.y * 128;
  if (tid < 128) frow[tid] = scales[4] / s3[r0 + tid];
  const int lane = tid & 63, wv = tid >> 6;
  const int wr = wv >> 1, wc = wv & 1;
  const int lo = lane & 15, hi = lane >> 4;
  const int sr = tid >> 3;
  const int sp = tid & 7;
  v4i acc[4][4];
#pragma unroll
  for (int m = 0; m < 4; ++m)
#pragma unroll
    for (int n = 0; n < 4; ++n) acc[m][n] = (v4i){0, 0, 0, 0};
  for (int kt = 0; kt < 16; ++kt) {
    const int kb = kt * 128;
    __syncthreads();
#pragma unroll
    for (int i = 0; i < 4; ++i) {
      int r = i * 32 + sr;
      int src = kb + ((sp ^ (r & 7)) << 4);
      int lds = i * 4096 + wv * 1024;
      gld16(q3 + (size_t)(r0 + r) * 2048 + src, As + lds);
      gld16(tout + (size_t)(c0 + r) * 2048 + src, Bs + lds);
    }
    __syncthreads();
#pragma unroll
    for (int kh = 0; kh < 2; ++kh) {
      v4i a[4];
#pragma unroll
      for (int m = 0; m < 4; ++m) {
        int rr = wr * 64 + m * 16 + lo;
        int c = kh * 4 + hi;
        a[m] = *(const v4i*)&As[rr * 128 + ((c ^ (rr & 7)) << 4)];
      }
#pragma unroll
      for (int n = 0; n < 4; ++n) {
        int cc = wc * 64 + n * 16 + lo;
        int c = kh * 4 + hi;
        v4i b = *(const v4i*)&Bs[cc * 128 + ((c ^ (cc & 7)) << 4)];
#pragma unroll
        for (int m = 0; m < 4; ++m)
          acc[m][n] = __builtin_amdgcn_mfma_i32_16x16x64_i8(a[m], b, acc[m][n], 0, 0, 0);
      }
    }
  }
#pragma unroll
  for (int m = 0; m < 4; ++m)
#pragma unroll
    for (int n = 0; n < 4; ++n)
#pragma unroll
      for (int rg = 0; rg < 4; ++rg) {
        int row = wr * 64 + m * 16 + hi * 4 + rg;
        int col = wc * 64 + n * 16 + lo;
        out[(size_t)(r0 + row) * 1024 + c0 + col] = (float)acc[m][n][rg] * frow[row];
      }
}

extern "C" void kernel_launch(void* const* d_in, const int* in_sizes, int n_in,
                              void* d_out, int out_size, void* d_ws, size_t ws_size,
                              hipStream_t stream) {
  const float* x     = (const float*)d_in[0];
  const float* win   = (const float*)d_in[1];
  const float* cw    = (const float*)d_in[2];
  const float* cb    = (const float*)d_in[3];
  const float* dw    = (const float*)d_in[4];
  const float* dbias = (const float*)d_in[5];
  const float* bw    = (const float*)d_in[6];
  const float* cmw   = (const float*)d_in[7];
  const float* ow    = (const float*)d_in[8];
  const float* Dp    = (const float*)d_in[9];
  const float* logA  = (const float*)d_in[10];
  float* out = (float*)d_out;

  char* p = (char*)d_ws;
  float* gated = (float*)p;   p += (size_t)4096 * 2048 * 4;  // 32MB
  float* xin   = (float*)p;   p += (size_t)4096 * 2048 * 4;  // 32MB
  char* qx_rgn = p;           p += (size_t)4096 * 1024;      // 4MB (reused as ipart after gemm1)
  char* tin_rgn = p;          p += (size_t)2 * 2048 * 1024;  // 4MB (reused as At/dBt/Ct/chb after gemm1)
  i8* tout = (i8*)p;          p += (size_t)1024 * 2048;      // 2MB
  i8* t2   = (i8*)p;          p += (size_t)48 * 2048;
  i8* q2   = (i8*)p;          p += (size_t)4096 * 2048;      // 8MB
  i8* q3   = (i8*)p;          p += (size_t)4096 * 2048;      // 8MB
  float* sx  = (float*)p;     p += (size_t)4096 * 4;
  float* s2  = (float*)p;     p += (size_t)4096 * 4;
  float* s3  = (float*)p;     p += (size_t)4096 * 4;
  float* scales = (float*)p;  p += 256;
  double* partial = (double*)p;

  i8* qx  = (i8*)qx_rgn;
  i8* tin = (i8*)tin_rgn;
  int* ipart = (int*)qx_rgn;              // alive only after gemm1 is done
  float* At  = (float*)tin_rgn;           // 32*2048 floats each, alive after gemm1
  float* dBt = At + 65536;
  float* Ct  = dBt + 65536;
  float* chb = Ct + 65536;

  // weight scales (fp64 deterministic) + ternary quant
  k_abssum_all<<<432, 256, 0, stream>>>(win, dw, bw, cmw, ow, partial);
  k_finalize<<<1, 64, 0, stream>>>(partial, scales);
  k_wquant_all<<<6240, 256, 0, stream>>>(win, dw, bw, cmw, ow, scales, tin, t2, tout);

  // pipeline
  k_actquant<1024><<<4096, 256, 0, stream>>>(x, qx, sx);
  k_gemm1<<<dim3(32, 16), 256, 0, stream>>>(qx, tin, sx, scales, gated);
  k_convq<<<4096, 256, 0, stream>>>(gated, cw, cb, xin, q2, s2);
  k_gemm2<<<dim3(64, 2), 256, 0, stream>>>(q2, t2, ipart);
  k_xform<<<256, 256, 0, stream>>>(ipart, s2, scales, dbias, logA, At, dBt, Ct);
  k_scan<<<32, 256, 0, stream>>>(At, dBt, Ct, chb);
  k_yq<<<4096, 256, 0, stream>>>(xin, chb, Dp, q3, s3);
  k_gemm3<<<dim3(32, 8), 256, 0, stream>>>(q3, tout, s3, scales, out);
}

// Round 3
// 163.558 us; speedup vs baseline: 1.5026x; 1.1027x over previous
//
#include <hip/hip_runtime.h>
#include <hip/hip_bf16.h>

typedef signed char i8;
typedef int v4i __attribute__((ext_vector_type(4)));

#define LSTR 80  // LDS row stride (bytes) for gemm2 staging

__device__ __forceinline__ void gld16(const void* g, void* l) {
  __builtin_amdgcn_global_load_lds(
      (const __attribute__((address_space(1))) unsigned int*)g,
      (__attribute__((address_space(3))) unsigned int*)l, 16, 0, 0);
}

// ---------------- merged |w| abs-sum (fp64, deterministic layout) ----------------
__global__ __launch_bounds__(256) void k_abssum_all(const float* __restrict__ w0, const float* __restrict__ w1,
                                                    const float* __restrict__ w2, const float* __restrict__ w3,
                                                    const float* __restrict__ w4, double* __restrict__ partial) {
  int b = blockIdx.x;
  const float* w; int n, nb, bg;
  if (b < 256)      { w = w0; n = 4194304; nb = 256; bg = b; }
  else if (b < 272) { w = w1; n = 32768;   nb = 16;  bg = b - 256; }
  else if (b < 288) { w = w2; n = 32768;   nb = 16;  bg = b - 272; }
  else if (b < 304) { w = w3; n = 32768;   nb = 16;  bg = b - 288; }
  else              { w = w4; n = 2097152; nb = 128; bg = b - 304; }
  __shared__ double sd[256];
  double acc = 0.0;
  for (int i = bg * 256 + threadIdx.x; i < n; i += nb * 256) acc += (double)fabsf(w[i]);
  sd[threadIdx.x] = acc;
  __syncthreads();
  for (int s = 128; s > 0; s >>= 1) {
    if (threadIdx.x < s) sd[threadIdx.x] += sd[threadIdx.x + s];
    __syncthreads();
  }
  if (threadIdx.x == 0) partial[b] = sd[0];
}

__global__ void k_finalize(const double* __restrict__ partial, float* __restrict__ scales) {
  int m = threadIdx.x;
  if (m >= 5) return;
  const int off[6] = {0, 256, 272, 288, 304, 432};
  const double cnt[5] = {4194304.0, 32768.0, 32768.0, 32768.0, 2097152.0};
  double s = 0.0;
  for (int i = off[m]; i < off[m + 1]; ++i) s += partial[i];
  scales[m] = fmaxf((float)(s / cnt[m]), 1e-5f);
}

// ---------------- merged ternary weight quant ----------------
__global__ __launch_bounds__(256) void k_wquant_all(const float* __restrict__ w0, const float* __restrict__ w1,
                                                    const float* __restrict__ w2, const float* __restrict__ w3,
                                                    const float* __restrict__ w4, const float* __restrict__ scales,
                                                    i8* __restrict__ tin, i8* __restrict__ t2, i8* __restrict__ tout) {
  int b = blockIdx.x;
  const float* w; i8* t; int m, n;
  if (b < 4096)      { w = w0; t = tin;          m = 0; n = 4194304; }
  else if (b < 4128) { w = w1; t = t2;           m = 1; n = 32768; b -= 4096; }
  else if (b < 4160) { w = w2; t = t2 + 32768;   m = 2; n = 32768; b -= 4128; }
  else if (b < 4192) { w = w3; t = t2 + 65536;   m = 3; n = 32768; b -= 4160; }
  else               { w = w4; t = tout;         m = 4; n = 2097152; b -= 4192; }
  int idx = (b * 256 + threadIdx.x) * 4;
  if (idx >= n) return;
  float scale = scales[m];
  float4 v = *(const float4*)(w + idx);
  char4 q;
  q.x = (i8)fminf(fmaxf(rintf(v.x / scale), -1.f), 1.f);
  q.y = (i8)fminf(fmaxf(rintf(v.y / scale), -1.f), 1.f);
  q.z = (i8)fminf(fmaxf(rintf(v.z / scale), -1.f), 1.f);
  q.w = (i8)fminf(fmaxf(rintf(v.w / scale), -1.f), 1.f);
  *(char4*)(t + idx) = q;
}

// ---------------- per-row activation quant (bit-exact vs reference) ----------------
template <int W>
__global__ __launch_bounds__(256) void k_actquant(const float* __restrict__ x,
                                                  i8* __restrict__ q, float* __restrict__ srow) {
  constexpr int E = W / 256;
  const int r = blockIdx.x, tid = threadIdx.x;
  const float* xr = x + (size_t)r * W;
  float v[E];
  float m = 0.f;
#pragma unroll
  for (int j = 0; j < E; j += 4) {
    float4 t = *(const float4*)(xr + tid * E + j);
    v[j] = t.x; v[j + 1] = t.y; v[j + 2] = t.z; v[j + 3] = t.w;
    m = fmaxf(m, fmaxf(fmaxf(fabsf(t.x), fabsf(t.y)), fmaxf(fabsf(t.z), fabsf(t.w))));
  }
  __shared__ float sm[4];
  __shared__ float sbc;
#pragma unroll
  for (int off = 32; off > 0; off >>= 1) m = fmaxf(m, __shfl_xor(m, off));
  if ((tid & 63) == 0) sm[tid >> 6] = m;
  __syncthreads();
  if (tid == 0) {
    float mm = fmaxf(fmaxf(sm[0], sm[1]), fmaxf(sm[2], sm[3]));
    float s = 127.0f / fmaxf(mm, 1e-5f);
    sbc = s;
    srow[r] = s;
  }
  __syncthreads();
  float s = sbc;
#pragma unroll
  for (int j = 0; j < E; j += 4) {
    char4 c;
    c.x = (i8)fminf(fmaxf(rintf(v[j] * s), -128.f), 127.f);
    c.y = (i8)fminf(fmaxf(rintf(v[j + 1] * s), -128.f), 127.f);
    c.z = (i8)fminf(fmaxf(rintf(v[j + 2] * s), -128.f), 127.f);
    c.w = (i8)fminf(fmaxf(rintf(v[j + 3] * s), -128.f), 127.f);
    *(char4*)(q + (size_t)r * W + tid * E + j) = c;
  }
}

// ---------------- GEMM1: 128x128 tile, BK=128, global_load_lds + XOR swizzle ----------------
__global__ __launch_bounds__(256) void k_gemm1(const i8* __restrict__ qx, const i8* __restrict__ tin,
                                               const float* __restrict__ sx, const float* __restrict__ scales,
                                               float* __restrict__ gated) {
  __shared__ i8 As[16384], Bg[16384], Bv[16384];
  __shared__ float frow[128];
  const int tid = threadIdx.x;
  const int r0 = blockIdx.x * 128, c0 = blockIdx.y * 128;
  if (tid < 128) frow[tid] = scales[0] / sx[r0 + tid];
  const int lane = tid & 63, wv = tid >> 6;
  const int wr = wv >> 1, wc = wv & 1;
  const int lo = lane & 15, hi = lane >> 4;
  const int sr = tid >> 3;
  const int sp = tid & 7;
  v4i accg[4][4], accv[4][4];
#pragma unroll
  for (int m = 0; m < 4; ++m)
#pragma unroll
    for (int n = 0; n < 4; ++n) {
      accg[m][n] = (v4i){0, 0, 0, 0};
      accv[m][n] = (v4i){0, 0, 0, 0};
    }
  for (int kt = 0; kt < 8; ++kt) {
    const int kb = kt * 128;
    __syncthreads();
#pragma unroll
    for (int i = 0; i < 4; ++i) {
      int r = i * 32 + sr;
      int src = kb + ((sp ^ (r & 7)) << 4);
      int lds = i * 4096 + wv * 1024;
      gld16(qx + (size_t)(r0 + r) * 1024 + src, As + lds);
      gld16(tin + (size_t)(c0 + r) * 1024 + src, Bg + lds);
      gld16(tin + (size_t)(2048 + c0 + r) * 1024 + src, Bv + lds);
    }
    __syncthreads();
#pragma unroll
    for (int kh = 0; kh < 2; ++kh) {
      v4i a[4];
#pragma unroll
      for (int m = 0; m < 4; ++m) {
        int rr = wr * 64 + m * 16 + lo;
        int c = kh * 4 + hi;
        a[m] = *(const v4i*)&As[rr * 128 + ((c ^ (rr & 7)) << 4)];
      }
#pragma unroll
      for (int n = 0; n < 4; ++n) {
        int cc = wc * 64 + n * 16 + lo;
        int c = kh * 4 + hi;
        int off = cc * 128 + ((c ^ (cc & 7)) << 4);
        v4i bg = *(const v4i*)&Bg[off];
        v4i bv = *(const v4i*)&Bv[off];
#pragma unroll
        for (int m = 0; m < 4; ++m) {
          accg[m][n] = __builtin_amdgcn_mfma_i32_16x16x64_i8(a[m], bg, accg[m][n], 0, 0, 0);
          accv[m][n] = __builtin_amdgcn_mfma_i32_16x16x64_i8(a[m], bv, accv[m][n], 0, 0, 0);
        }
      }
    }
  }
#pragma unroll
  for (int m = 0; m < 4; ++m)
#pragma unroll
    for (int n = 0; n < 4; ++n)
#pragma unroll
      for (int rg = 0; rg < 4; ++rg) {
        int row = wr * 64 + m * 16 + hi * 4 + rg;
        int col = wc * 64 + n * 16 + lo;
        float f = frow[row];
        float g = (float)accg[m][n][rg] * f;
        float v = (float)accv[m][n][rg] * f;
        float sg = 1.0f / (1.0f + expf(-g));
        gated[(size_t)(r0 + row) * 2048 + c0 + col] = g * sg * v;
      }
}

// ---------------- fused causal depthwise conv + act-quant, 8 rows/block ----------------
__global__ __launch_bounds__(256) void k_convq(const float* __restrict__ g, const float* __restrict__ cw,
                                               const float* __restrict__ cb, float* __restrict__ xo,
                                               i8* __restrict__ q, float* __restrict__ srow) {
  const int tid = threadIdx.x;
  const int r0 = blockIdx.x * 8;        // 512 blocks, never crosses batch boundary
  const int l0 = r0 & 2047;
  const int ch = tid * 8;
  const int lane = tid & 63, wv = tid >> 6;
  float wt[4][8];
#pragma unroll
  for (int j = 0; j < 8; ++j) {
    float4 w = *(const float4*)(cw + (ch + j) * 4);
    wt[0][j] = w.x; wt[1][j] = w.y; wt[2][j] = w.z; wt[3][j] = w.w;
  }
  float bias[8];
  {
    float4 b0 = *(const float4*)(cb + ch), b1 = *(const float4*)(cb + ch + 4);
    bias[0] = b0.x; bias[1] = b0.y; bias[2] = b0.z; bias[3] = b0.w;
    bias[4] = b1.x; bias[5] = b1.y; bias[6] = b1.z; bias[7] = b1.w;
  }
  const float* gb = g + (size_t)r0 * 2048 + ch;
  float wm3[8], wm2[8], wm1[8];
  if (l0 != 0) {  // block-uniform: halo rows exist
    float4 a, b;
    a = *(const float4*)(gb - 3 * 2048); b = *(const float4*)(gb - 3 * 2048 + 4);
    wm3[0]=a.x; wm3[1]=a.y; wm3[2]=a.z; wm3[3]=a.w; wm3[4]=b.x; wm3[5]=b.y; wm3[6]=b.z; wm3[7]=b.w;
    a = *(const float4*)(gb - 2 * 2048); b = *(const float4*)(gb - 2 * 2048 + 4);
    wm2[0]=a.x; wm2[1]=a.y; wm2[2]=a.z; wm2[3]=a.w; wm2[4]=b.x; wm2[5]=b.y; wm2[6]=b.z; wm2[7]=b.w;
    a = *(const float4*)(gb - 1 * 2048); b = *(const float4*)(gb - 1 * 2048 + 4);
    wm1[0]=a.x; wm1[1]=a.y; wm1[2]=a.z; wm1[3]=a.w; wm1[4]=b.x; wm1[5]=b.y; wm1[6]=b.z; wm1[7]=b.w;
  } else {
#pragma unroll
    for (int j = 0; j < 8; ++j) { wm3[j] = 0.f; wm2[j] = 0.f; wm1[j] = 0.f; }
  }
  float* xop = xo + (size_t)r0 * 2048 + ch;
  float rowmax[8];
#pragma unroll
  for (int l = 0; l < 8; ++l) {
    float cur[8];
    {
      float4 a = *(const float4*)(gb + l * 2048), b = *(const float4*)(gb + l * 2048 + 4);
      cur[0]=a.x; cur[1]=a.y; cur[2]=a.z; cur[3]=a.w; cur[4]=b.x; cur[5]=b.y; cur[6]=b.z; cur[7]=b.w;
    }
    float acc[8];
    float m = 0.f;
#pragma unroll
    for (int j = 0; j < 8; ++j) {
      float v = bias[j];
      v = fmaf(wt[0][j], wm3[j], v);
      v = fmaf(wt[1][j], wm2[j], v);
      v = fmaf(wt[2][j], wm1[j], v);
      v = fmaf(wt[3][j], cur[j], v);
      acc[j] = v;
      m = fmaxf(m, fabsf(v));
    }
    rowmax[l] = m;
    *(float4*)(xop + l * 2048) = make_float4(acc[0], acc[1], acc[2], acc[3]);
    *(float4*)(xop + l * 2048 + 4) = make_float4(acc[4], acc[5], acc[6], acc[7]);
#pragma unroll
    for (int j = 0; j < 8; ++j) { wm3[j] = wm2[j]; wm2[j] = wm1[j]; wm1[j] = cur[j]; }
  }
  __shared__ float sred[8][4];
  __shared__ float sscale[8];
#pragma unroll
  for (int l = 0; l < 8; ++l) {
    float m = rowmax[l];
#pragma unroll
    for (int off = 32; off > 0; off >>= 1) m = fmaxf(m, __shfl_xor(m, off));
    if (lane == 0) sred[l][wv] = m;
  }
  __syncthreads();
  if (tid < 8) {
    float mm = fmaxf(fmaxf(sred[tid][0], sred[tid][1]), fmaxf(sred[tid][2], sred[tid][3]));
    float s = 127.0f / fmaxf(mm, 1e-5f);
    sscale[tid] = s;
    srow[r0 + tid] = s;
  }
  __syncthreads();
  i8* qp = q + (size_t)r0 * 2048 + ch;
#pragma unroll
  for (int l = 0; l < 8; ++l) {
    float s = sscale[l];
    float4 a = *(const float4*)(xop + l * 2048);      // L1/L2 hit: our own write
    float4 b = *(const float4*)(xop + l * 2048 + 4);
    char4 c0q, c1q;
    c0q.x = (i8)fminf(fmaxf(rintf(a.x * s), -128.f), 127.f);
    c0q.y = (i8)fminf(fmaxf(rintf(a.y * s), -128.f), 127.f);
    c0q.z = (i8)fminf(fmaxf(rintf(a.z * s), -128.f), 127.f);
    c0q.w = (i8)fminf(fmaxf(rintf(a.w * s), -128.f), 127.f);
    c1q.x = (i8)fminf(fmaxf(rintf(b.x * s), -128.f), 127.f);
    c1q.y = (i8)fminf(fmaxf(rintf(b.y * s), -128.f), 127.f);
    c1q.z = (i8)fminf(fmaxf(rintf(b.z * s), -128.f), 127.f);
    c1q.w = (i8)fminf(fmaxf(rintf(b.w * s), -128.f), 127.f);
    *(char4*)(qp + l * 2048) = c0q;
    *(char4*)(qp + l * 2048 + 4) = c1q;
  }
}

// ---------------- GEMM2: K-split i32 partials, [4096 x 1024y] @ [48 x K]^T ----------------
__global__ __launch_bounds__(256) void k_gemm2(const i8* __restrict__ q2, const i8* __restrict__ t2,
                                               int* __restrict__ ipart) {
  __shared__ i8 As[64 * LSTR];
  __shared__ i8 Bs[48 * LSTR];
  const int tid = threadIdx.x;
  const int r0 = blockIdx.x * 64;
  const int kb = blockIdx.y * 1024;
  const int lrow = tid >> 2, lk = (tid & 3) * 16;
  const int lane = tid & 63, wv = tid >> 6;
  const int fr = lane & 15, fk = (lane >> 4) * 16;
  v4i acc[3];
#pragma unroll
  for (int s = 0; s < 3; ++s) acc[s] = (v4i){0, 0, 0, 0};
  for (int ks = 0; ks < 16; ++ks) {
    const int k0 = kb + ks * 64;
    __syncthreads();
    *(v4i*)&As[lrow * LSTR + lk] = *(const v4i*)&q2[(size_t)(r0 + lrow) * 2048 + k0 + lk];
    if (tid < 192)
      *(v4i*)&Bs[(tid >> 2) * LSTR + (tid & 3) * 16] = *(const v4i*)&t2[(size_t)(tid >> 2) * 2048 + k0 + (tid & 3) * 16];
    __syncthreads();
    v4i a = *(const v4i*)&As[(wv * 16 + fr) * LSTR + fk];
#pragma unroll
    for (int s = 0; s < 3; ++s) {
      v4i b = *(const v4i*)&Bs[(s * 16 + fr) * LSTR + fk];
      acc[s] = __builtin_amdgcn_mfma_i32_16x16x64_i8(a, b, acc[s], 0, 0, 0);
    }
  }
#pragma unroll
  for (int s = 0; s < 3; ++s)
#pragma unroll
    for (int rg = 0; rg < 4; ++rg) {
      int row = wv * 16 + (lane >> 4) * 4 + rg;
      int col = s * 16 + (lane & 15);
      ipart[(size_t)blockIdx.y * 196608 + (size_t)(r0 + row) * 48 + col] = acc[s][rg];
    }
}

// ---------------- combine partials, dequant, build A_d / delta*B / C transposed ----------------
__global__ __launch_bounds__(256) void k_xform(const int* __restrict__ ip, const float* __restrict__ s2,
                                               const float* __restrict__ scales, const float* __restrict__ dbias,
                                               const float* __restrict__ logA, float* __restrict__ At,
                                               float* __restrict__ dBt, float* __restrict__ Ct) {
  int idx = blockIdx.x * 256 + threadIdx.x;
  int r = idx >> 4, n = idx & 15;
  int b = r >> 11, l = r & 2047;
  float fr = 1.0f / s2[r];
  int base = r * 48;
  float dd = (float)(ip[base + n] + ip[196608 + base + n]) * (scales[1] * fr) + dbias[n];
  float Bv = (float)(ip[base + 16 + n] + ip[196608 + base + 16 + n]) * (scales[2] * fr);
  float Cv = (float)(ip[base + 32 + n] + ip[196608 + base + 32 + n]) * (scales[3] * fr);
  int o = ((b * 16 + n) << 11) | l;
  At[o] = expf(dd * logA[n]);
  dBt[o] = dd * Bv;
  Ct[o] = Cv;
}

// ---------------- parallel scan over time per (b,n) ----------------
__global__ __launch_bounds__(256) void k_scan(const float* __restrict__ At, const float* __restrict__ dBt,
                                              const float* __restrict__ Ct, float* __restrict__ ch) {
  const int i = threadIdx.x;
  const int base = blockIdx.x << 11;
  float a[8], db[8], c[8];
  {
    const float4* p = (const float4*)(At + base + i * 8);
    float4 t0 = p[0], t1 = p[1];
    a[0]=t0.x; a[1]=t0.y; a[2]=t0.z; a[3]=t0.w; a[4]=t1.x; a[5]=t1.y; a[6]=t1.z; a[7]=t1.w;
  }
  {
    const float4* p = (const float4*)(dBt + base + i * 8);
    float4 t0 = p[0], t1 = p[1];
    db[0]=t0.x; db[1]=t0.y; db[2]=t0.z; db[3]=t0.w; db[4]=t1.x; db[5]=t1.y; db[6]=t1.z; db[7]=t1.w;
  }
  {
    const float4* p = (const float4*)(Ct + base + i * 8);
    float4 t0 = p[0], t1 = p[1];
    c[0]=t0.x; c[1]=t0.y; c[2]=t0.z; c[3]=t0.w; c[4]=t1.x; c[5]=t1.y; c[6]=t1.z; c[7]=t1.w;
  }
  float Ac = 1.f, Bc = 0.f;
#pragma unroll
  for (int j = 0; j < 8; ++j) { Bc = a[j] * Bc + db[j]; Ac *= a[j]; }
  __shared__ float sA[256], sB[256];
  sA[i] = Ac; sB[i] = Bc;
  __syncthreads();
  for (int off = 1; off < 256; off <<= 1) {
    float pA = 1.f, pB = 0.f;
    if (i >= off) { pA = sA[i - off]; pB = sB[i - off]; }
    __syncthreads();
    Bc = Ac * pB + Bc;
    Ac = Ac * pA;
    sA[i] = Ac; sB[i] = Bc;
    __syncthreads();
  }
  float h = (i > 0) ? sB[i - 1] : 0.f;
  float o[8];
#pragma unroll
  for (int j = 0; j < 8; ++j) { h = a[j] * h + db[j]; o[j] = c[j] * h; }
  float4* po = (float4*)(ch + base + i * 8);
  po[0] = make_float4(o[0], o[1], o[2], o[3]);
  po[1] = make_float4(o[4], o[5], o[6], o[7]);
}

// ---------------- y_inner scaling + act-quant, 8 rows/block ----------------
__global__ __launch_bounds__(256) void k_yq(const float* __restrict__ xin, const float* __restrict__ chb,
                                            const float* __restrict__ Dp, i8* __restrict__ q,
                                            float* __restrict__ srow) {
  const int tid = threadIdx.x;
  const int r0 = blockIdx.x * 8;
  const int b = r0 >> 11, l0 = r0 & 2047;
  const int lane = tid & 63, wv = tid >> 6;
  __shared__ float ssig[8 * 16];
  __shared__ float ssg[8];
  __shared__ float sred[8][4];
  __shared__ float sscale[8];
  if (tid < 128) {
    int n = tid >> 3, li = tid & 7;
    ssig[li * 16 + n] = chb[((size_t)(b * 16 + n) << 11) | (l0 + li)];
  }
  __syncthreads();
  if (tid < 8) {
    float s = 0.f;
    for (int n = 0; n < 16; ++n) s += ssig[tid * 16 + n];
    ssg[tid] = 1.0f / (1.0f + expf(-s));
  }
  __syncthreads();
  const int ch = tid * 8;
  float dreg[8];
  {
    float4 d0 = *(const float4*)(Dp + ch), d1 = *(const float4*)(Dp + ch + 4);
    dreg[0]=d0.x; dreg[1]=d0.y; dreg[2]=d0.z; dreg[3]=d0.w;
    dreg[4]=d1.x; dreg[5]=d1.y; dreg[6]=d1.z; dreg[7]=d1.w;
  }
  const float* xr = xin + (size_t)r0 * 2048 + ch;
  float rowmax[8];
#pragma unroll
  for (int l = 0; l < 8; ++l) {
    float sg = ssg[l];
    float4 a = *(const float4*)(xr + l * 2048);
    float4 c = *(const float4*)(xr + l * 2048 + 4);
    float m = 0.f;
    m = fmaxf(m, fabsf(a.x * (sg + dreg[0])));
    m = fmaxf(m, fabsf(a.y * (sg + dreg[1])));
    m = fmaxf(m, fabsf(a.z * (sg + dreg[2])));
    m = fmaxf(m, fabsf(a.w * (sg + dreg[3])));
    m = fmaxf(m, fabsf(c.x * (sg + dreg[4])));
    m = fmaxf(m, fabsf(c.y * (sg + dreg[5])));
    m = fmaxf(m, fabsf(c.z * (sg + dreg[6])));
    m = fmaxf(m, fabsf(c.w * (sg + dreg[7])));
    rowmax[l] = m;
  }
#pragma unroll
  for (int l = 0; l < 8; ++l) {
    float m = rowmax[l];
#pragma unroll
    for (int off = 32; off > 0; off >>= 1) m = fmaxf(m, __shfl_xor(m, off));
    if (lane == 0) sred[l][wv] = m;
  }
  __syncthreads();
  if (tid < 8) {
    float mm = fmaxf(fmaxf(sred[tid][0], sred[tid][1]), fmaxf(sred[tid][2], sred[tid][3]));
    float s = 127.0f / fmaxf(mm, 1e-5f);
    sscale[tid] = s;
    srow[r0 + tid] = s;
  }
  __syncthreads();
  i8* qp = q + (size_t)r0 * 2048 + ch;
#pragma unroll
  for (int l = 0; l < 8; ++l) {
    float s = sscale[l];
    float sg = ssg[l];
    float4 a = *(const float4*)(xr + l * 2048);      // L1/L2 hit
    float4 c = *(const float4*)(xr + l * 2048 + 4);
    char4 c0q, c1q;
    c0q.x = (i8)fminf(fmaxf(rintf(a.x * (sg + dreg[0]) * s), -128.f), 127.f);
    c0q.y = (i8)fminf(fmaxf(rintf(a.y * (sg + dreg[1]) * s), -128.f), 127.f);
    c0q.z = (i8)fminf(fmaxf(rintf(a.z * (sg + dreg[2]) * s), -128.f), 127.f);
    c0q.w = (i8)fminf(fmaxf(rintf(a.w * (sg + dreg[3]) * s), -128.f), 127.f);
    c1q.x = (i8)fminf(fmaxf(rintf(c.x * (sg + dreg[4]) * s), -128.f), 127.f);
    c1q.y = (i8)fminf(fmaxf(rintf(c.y * (sg + dreg[5]) * s), -128.f), 127.f);
    c1q.z = (i8)fminf(fmaxf(rintf(c.z * (sg + dreg[6]) * s), -128.f), 127.f);
    c1q.w = (i8)fminf(fmaxf(rintf(c.w * (sg + dreg[7]) * s), -128.f), 127.f);
    *(char4*)(qp + l * 2048) = c0q;
    *(char4*)(qp + l * 2048 + 4) = c1q;
  }
}

// ---------------- GEMM3: 128x128 tile, BK=128, K=2048 ----------------
__global__ __launch_bounds__(256) void k_gemm3(const i8* __restrict__ q3, const i8* __restrict__ tout,
                                               const float* __restrict__ s3, const float* __restrict__ scales,
                                               float* __restrict__ out) {
  __shared__ i8 As[16384], Bs[16384];
  __shared__ float frow[128];
  const int tid = threadIdx.x;
  const int r0 = blockIdx.x * 128, c0 = blockIdx.y * 128;
  if (tid < 128) frow[tid] = scales[4] / s3[r0 + tid];
  const int lane = tid & 63, wv = tid >> 6;
  const int wr = wv >> 1, wc = wv & 1;
  const int lo = lane & 15, hi = lane >> 4;
  const int sr = tid >> 3;
  const int sp = tid & 7;
  v4i acc[4][4];
#pragma unroll
  for (int m = 0; m < 4; ++m)
#pragma unroll
    for (int n = 0; n < 4; ++n) acc[m][n] = (v4i){0, 0, 0, 0};
  for (int kt = 0; kt < 16; ++kt) {
    const int kb = kt * 128;
    __syncthreads();
#pragma unroll
    for (int i = 0; i < 4; ++i) {
      int r = i * 32 + sr;
      int src = kb + ((sp ^ (r & 7)) << 4);
      int lds = i * 4096 + wv * 1024;
      gld16(q3 + (size_t)(r0 + r) * 2048 + src, As + lds);
      gld16(tout + (size_t)(c0 + r) * 2048 + src, Bs + lds);
    }
    __syncthreads();
#pragma unroll
    for (int kh = 0; kh < 2; ++kh) {
      v4i a[4];
#pragma unroll
      for (int m = 0; m < 4; ++m) {
        int rr = wr * 64 + m * 16 + lo;
        int c = kh * 4 + hi;
        a[m] = *(const v4i*)&As[rr * 128 + ((c ^ (rr & 7)) << 4)];
      }
#pragma unroll
      for (int n = 0; n < 4; ++n) {
        int cc = wc * 64 + n * 16 + lo;
        int c = kh * 4 + hi;
        v4i b = *(const v4i*)&Bs[cc * 128 + ((c ^ (cc & 7)) << 4)];
#pragma unroll
        for (int m = 0; m < 4; ++m)
          acc[m][n] = __builtin_amdgcn_mfma_i32_16x16x64_i8(a[m], b, acc[m][n], 0, 0, 0);
      }
    }
  }
#pragma unroll
  for (int m = 0; m < 4; ++m)
#pragma unroll
    for (int n = 0; n < 4; ++n)
#pragma unroll
      for (int rg = 0; rg < 4; ++rg) {
        int row = wr * 64 + m * 16 + hi * 4 + rg;
        int col = wc * 64 + n * 16 + lo;
        out[(size_t)(r0 + row) * 1024 + c0 + col] = (float)acc[m][n][rg] * frow[row];
      }
}

extern "C" void kernel_launch(void* const* d_in, const int* in_sizes, int n_in,
                              void* d_out, int out_size, void* d_ws, size_t ws_size,
                              hipStream_t stream) {
  const float* x     = (const float*)d_in[0];
  const float* win   = (const float*)d_in[1];
  const float* cw    = (const float*)d_in[2];
  const float* cb    = (const float*)d_in[3];
  const float* dw    = (const float*)d_in[4];
  const float* dbias = (const float*)d_in[5];
  const float* bw    = (const float*)d_in[6];
  const float* cmw   = (const float*)d_in[7];
  const float* ow    = (const float*)d_in[8];
  const float* Dp    = (const float*)d_in[9];
  const float* logA  = (const float*)d_in[10];
  float* out = (float*)d_out;

  char* p = (char*)d_ws;
  float* gated = (float*)p;   p += (size_t)4096 * 2048 * 4;
  float* xin   = (float*)p;   p += (size_t)4096 * 2048 * 4;
  char* qx_rgn = p;           p += (size_t)4096 * 1024;
  char* tin_rgn = p;          p += (size_t)2 * 2048 * 1024;
  i8* tout = (i8*)p;          p += (size_t)1024 * 2048;
  i8* t2   = (i8*)p;          p += (size_t)48 * 2048;
  i8* q2   = (i8*)p;          p += (size_t)4096 * 2048;
  i8* q3   = (i8*)p;          p += (size_t)4096 * 2048;
  float* sx  = (float*)p;     p += (size_t)4096 * 4;
  float* s2  = (float*)p;     p += (size_t)4096 * 4;
  float* s3  = (float*)p;     p += (size_t)4096 * 4;
  float* scales = (float*)p;  p += 256;
  double* partial = (double*)p;

  i8* qx  = (i8*)qx_rgn;
  i8* tin = (i8*)tin_rgn;
  int* ipart = (int*)qx_rgn;
  float* At  = (float*)tin_rgn;
  float* dBt = At + 65536;
  float* Ct  = dBt + 65536;
  float* chb = Ct + 65536;

  k_abssum_all<<<432, 256, 0, stream>>>(win, dw, bw, cmw, ow, partial);
  k_finalize<<<1, 64, 0, stream>>>(partial, scales);
  k_wquant_all<<<6240, 256, 0, stream>>>(win, dw, bw, cmw, ow, scales, tin, t2, tout);

  k_actquant<1024><<<4096, 256, 0, stream>>>(x, qx, sx);
  k_gemm1<<<dim3(32, 16), 256, 0, stream>>>(qx, tin, sx, scales, gated);
  k_convq<<<512, 256, 0, stream>>>(gated, cw, cb, xin, q2, s2);
  k_gemm2<<<dim3(64, 2), 256, 0, stream>>>(q2, t2, ipart);
  k_xform<<<256, 256, 0, stream>>>(ipart, s2, scales, dbias, logA, At, dBt, Ct);
  k_scan<<<32, 256, 0, stream>>>(At, dBt, Ct, chb);
  k_yq<<<512, 256, 0, stream>>>(xin, chb, Dp, q3, s3);
  k_gemm3<<<dim3(32, 8), 256, 0, stream>>>(q3, tout, s3, scales, out);
}

// Round 4
// 152.027 us; speedup vs baseline: 1.6165x; 1.0758x over previous
//
#include <hip/hip_runtime.h>
#include <hip/hip_bf16.h>

typedef signed char i8;
typedef int v4i __attribute__((ext_vector_type(4)));

#define LSTR 80  // LDS row stride (bytes) for gemm2 staging

__device__ __forceinline__ void gld16(const void* g, void* l) {
  __builtin_amdgcn_global_load_lds(
      (const __attribute__((address_space(1))) unsigned int*)g,
      (__attribute__((address_space(3))) unsigned int*)l, 16, 0, 0);
}

// ---------------- merged |w| abs-sum (fp64, deterministic layout) ----------------
__global__ __launch_bounds__(256) void k_abssum_all(const float* __restrict__ w0, const float* __restrict__ w1,
                                                    const float* __restrict__ w2, const float* __restrict__ w3,
                                                    const float* __restrict__ w4, double* __restrict__ partial) {
  int b = blockIdx.x;
  const float* w; int n, nb, bg;
  if (b < 256)      { w = w0; n = 4194304; nb = 256; bg = b; }
  else if (b < 272) { w = w1; n = 32768;   nb = 16;  bg = b - 256; }
  else if (b < 288) { w = w2; n = 32768;   nb = 16;  bg = b - 272; }
  else if (b < 304) { w = w3; n = 32768;   nb = 16;  bg = b - 288; }
  else              { w = w4; n = 2097152; nb = 128; bg = b - 304; }
  __shared__ double sd[256];
  double acc = 0.0;
  for (int i = bg * 256 + threadIdx.x; i < n; i += nb * 256) acc += (double)fabsf(w[i]);
  sd[threadIdx.x] = acc;
  __syncthreads();
  for (int s = 128; s > 0; s >>= 1) {
    if (threadIdx.x < s) sd[threadIdx.x] += sd[threadIdx.x + s];
    __syncthreads();
  }
  if (threadIdx.x == 0) partial[b] = sd[0];
}

__global__ void k_finalize(const double* __restrict__ partial, float* __restrict__ scales) {
  int m = threadIdx.x;
  if (m >= 5) return;
  const int off[6] = {0, 256, 272, 288, 304, 432};
  const double cnt[5] = {4194304.0, 32768.0, 32768.0, 32768.0, 2097152.0};
  double s = 0.0;
  for (int i = off[m]; i < off[m + 1]; ++i) s += partial[i];
  scales[m] = fmaxf((float)(s / cnt[m]), 1e-5f);
}

// ---------------- merged ternary weight quant ----------------
__global__ __launch_bounds__(256) void k_wquant_all(const float* __restrict__ w0, const float* __restrict__ w1,
                                                    const float* __restrict__ w2, const float* __restrict__ w3,
                                                    const float* __restrict__ w4, const float* __restrict__ scales,
                                                    i8* __restrict__ tin, i8* __restrict__ t2, i8* __restrict__ tout) {
  int b = blockIdx.x;
  const float* w; i8* t; int m, n;
  if (b < 4096)      { w = w0; t = tin;          m = 0; n = 4194304; }
  else if (b < 4128) { w = w1; t = t2;           m = 1; n = 32768; b -= 4096; }
  else if (b < 4160) { w = w2; t = t2 + 32768;   m = 2; n = 32768; b -= 4128; }
  else if (b < 4192) { w = w3; t = t2 + 65536;   m = 3; n = 32768; b -= 4160; }
  else               { w = w4; t = tout;         m = 4; n = 2097152; b -= 4192; }
  int idx = (b * 256 + threadIdx.x) * 4;
  if (idx >= n) return;
  float scale = scales[m];
  float4 v = *(const float4*)(w + idx);
  char4 q;
  q.x = (i8)fminf(fmaxf(rintf(v.x / scale), -1.f), 1.f);
  q.y = (i8)fminf(fmaxf(rintf(v.y / scale), -1.f), 1.f);
  q.z = (i8)fminf(fmaxf(rintf(v.z / scale), -1.f), 1.f);
  q.w = (i8)fminf(fmaxf(rintf(v.w / scale), -1.f), 1.f);
  *(char4*)(t + idx) = q;
}

// ---------------- per-row activation quant (bit-exact vs reference) ----------------
template <int W>
__global__ __launch_bounds__(256) void k_actquant(const float* __restrict__ x,
                                                  i8* __restrict__ q, float* __restrict__ srow) {
  constexpr int E = W / 256;
  const int r = blockIdx.x, tid = threadIdx.x;
  const float* xr = x + (size_t)r * W;
  float v[E];
  float m = 0.f;
#pragma unroll
  for (int j = 0; j < E; j += 4) {
    float4 t = *(const float4*)(xr + tid * E + j);
    v[j] = t.x; v[j + 1] = t.y; v[j + 2] = t.z; v[j + 3] = t.w;
    m = fmaxf(m, fmaxf(fmaxf(fabsf(t.x), fabsf(t.y)), fmaxf(fabsf(t.z), fabsf(t.w))));
  }
  __shared__ float sm[4];
  __shared__ float sbc;
#pragma unroll
  for (int off = 32; off > 0; off >>= 1) m = fmaxf(m, __shfl_xor(m, off));
  if ((tid & 63) == 0) sm[tid >> 6] = m;
  __syncthreads();
  if (tid == 0) {
    float mm = fmaxf(fmaxf(sm[0], sm[1]), fmaxf(sm[2], sm[3]));
    float s = 127.0f / fmaxf(mm, 1e-5f);
    sbc = s;
    srow[r] = s;
  }
  __syncthreads();
  float s = sbc;
#pragma unroll
  for (int j = 0; j < E; j += 4) {
    char4 c;
    c.x = (i8)fminf(fmaxf(rintf(v[j] * s), -128.f), 127.f);
    c.y = (i8)fminf(fmaxf(rintf(v[j + 1] * s), -128.f), 127.f);
    c.z = (i8)fminf(fmaxf(rintf(v[j + 2] * s), -128.f), 127.f);
    c.w = (i8)fminf(fmaxf(rintf(v[j + 3] * s), -128.f), 127.f);
    *(char4*)(q + (size_t)r * W + tid * E + j) = c;
  }
}

// ---------------- GEMM1: 128x128 tile, BK=64, 2-phase double-buffered pipeline ----------------
#define COMPUTE1(Ab, Gb, Vb)                                                        \
  {                                                                                 \
    v4i a[4];                                                                       \
    _Pragma("unroll") for (int m = 0; m < 4; ++m) {                                 \
      int rr = wr * 64 + m * 16 + lo;                                               \
      a[m] = *(const v4i*)&Ab[rr * 64 + ((hi ^ (rr & 3)) << 4)];                    \
    }                                                                               \
    __builtin_amdgcn_s_setprio(1);                                                  \
    _Pragma("unroll") for (int n = 0; n < 4; ++n) {                                 \
      int cc = wc * 64 + n * 16 + lo;                                               \
      int off = cc * 64 + ((hi ^ (cc & 3)) << 4);                                   \
      v4i bg = *(const v4i*)&Gb[off];                                               \
      v4i bv = *(const v4i*)&Vb[off];                                               \
      _Pragma("unroll") for (int m = 0; m < 4; ++m) {                               \
        accg[m][n] = __builtin_amdgcn_mfma_i32_16x16x64_i8(a[m], bg, accg[m][n], 0, 0, 0); \
        accv[m][n] = __builtin_amdgcn_mfma_i32_16x16x64_i8(a[m], bv, accv[m][n], 0, 0, 0); \
      }                                                                             \
    }                                                                               \
    __builtin_amdgcn_s_setprio(0);                                                  \
  }

#define SYNCPIPE                                             \
  asm volatile("s_waitcnt vmcnt(0)" ::: "memory");           \
  __builtin_amdgcn_s_barrier();

__global__ __launch_bounds__(256) void k_gemm1(const i8* __restrict__ qx, const i8* __restrict__ tin,
                                               const float* __restrict__ sx, const float* __restrict__ scales,
                                               float* __restrict__ gated) {
  __shared__ i8 A0[8192], A1[8192], G0[8192], G1[8192], V0[8192], V1[8192];
  __shared__ float frow[128];
  const int tid = threadIdx.x;
  const int r0 = blockIdx.x * 128, c0 = blockIdx.y * 128;
  if (tid < 128) frow[tid] = scales[0] / sx[r0 + tid];
  __syncthreads();
  const int lane = tid & 63, wv = tid >> 6;
  const int wr = wv >> 1, wc = wv & 1;
  const int lo = lane & 15, hi = lane >> 4;
  const int srw = wv * 16 + (lane >> 2);   // staged row (i*64 + srw)
  const int sc = lane & 3;                 // staged logical chunk base
  v4i accg[4][4], accv[4][4];
#pragma unroll
  for (int m = 0; m < 4; ++m)
#pragma unroll
    for (int n = 0; n < 4; ++n) {
      accg[m][n] = (v4i){0, 0, 0, 0};
      accv[m][n] = (v4i){0, 0, 0, 0};
    }

#define STAGE1(kt, Ab, Gb, Vb)                                           \
  {                                                                      \
    const int kb = (kt)*64;                                              \
    _Pragma("unroll") for (int i = 0; i < 2; ++i) {                      \
      int r = i * 64 + srw;                                              \
      int src = kb + ((sc ^ (r & 3)) << 4);                              \
      int db = i * 4096 + wv * 1024;                                     \
      gld16(qx + (size_t)(r0 + r) * 1024 + src, Ab + db);                \
      gld16(tin + (size_t)(c0 + r) * 1024 + src, Gb + db);               \
      gld16(tin + (size_t)(2048 + c0 + r) * 1024 + src, Vb + db);        \
    }                                                                    \
  }

  STAGE1(0, A0, G0, V0);
  SYNCPIPE;
#pragma unroll
  for (int kt = 0; kt < 16; kt += 2) {
    STAGE1(kt + 1, A1, G1, V1);
    COMPUTE1(A0, G0, V0);
    SYNCPIPE;
    if (kt + 2 < 16) STAGE1(kt + 2, A0, G0, V0);
    COMPUTE1(A1, G1, V1);
    SYNCPIPE;
  }
#undef STAGE1

#pragma unroll
  for (int m = 0; m < 4; ++m)
#pragma unroll
    for (int n = 0; n < 4; ++n)
#pragma unroll
      for (int rg = 0; rg < 4; ++rg) {
        int row = wr * 64 + m * 16 + hi * 4 + rg;
        int col = wc * 64 + n * 16 + lo;
        float f = frow[row];
        float g = (float)accg[m][n][rg] * f;
        float v = (float)accv[m][n][rg] * f;
        float sg = 1.0f / (1.0f + expf(-g));
        gated[(size_t)(r0 + row) * 2048 + c0 + col] = g * sg * v;
      }
}

// ---------------- fused causal depthwise conv + act-quant, 8 rows/block ----------------
__global__ __launch_bounds__(256) void k_convq(const float* __restrict__ g, const float* __restrict__ cw,
                                               const float* __restrict__ cb, float* __restrict__ xo,
                                               i8* __restrict__ q, float* __restrict__ srow) {
  const int tid = threadIdx.x;
  const int r0 = blockIdx.x * 8;
  const int l0 = r0 & 2047;
  const int ch = tid * 8;
  const int lane = tid & 63, wv = tid >> 6;
  float wt[4][8];
#pragma unroll
  for (int j = 0; j < 8; ++j) {
    float4 w = *(const float4*)(cw + (ch + j) * 4);
    wt[0][j] = w.x; wt[1][j] = w.y; wt[2][j] = w.z; wt[3][j] = w.w;
  }
  float bias[8];
  {
    float4 b0 = *(const float4*)(cb + ch), b1 = *(const float4*)(cb + ch + 4);
    bias[0] = b0.x; bias[1] = b0.y; bias[2] = b0.z; bias[3] = b0.w;
    bias[4] = b1.x; bias[5] = b1.y; bias[6] = b1.z; bias[7] = b1.w;
  }
  const float* gb = g + (size_t)r0 * 2048 + ch;
  float wm3[8], wm2[8], wm1[8];
  if (l0 != 0) {
    float4 a, b;
    a = *(const float4*)(gb - 3 * 2048); b = *(const float4*)(gb - 3 * 2048 + 4);
    wm3[0]=a.x; wm3[1]=a.y; wm3[2]=a.z; wm3[3]=a.w; wm3[4]=b.x; wm3[5]=b.y; wm3[6]=b.z; wm3[7]=b.w;
    a = *(const float4*)(gb - 2 * 2048); b = *(const float4*)(gb - 2 * 2048 + 4);
    wm2[0]=a.x; wm2[1]=a.y; wm2[2]=a.z; wm2[3]=a.w; wm2[4]=b.x; wm2[5]=b.y; wm2[6]=b.z; wm2[7]=b.w;
    a = *(const float4*)(gb - 1 * 2048); b = *(const float4*)(gb - 1 * 2048 + 4);
    wm1[0]=a.x; wm1[1]=a.y; wm1[2]=a.z; wm1[3]=a.w; wm1[4]=b.x; wm1[5]=b.y; wm1[6]=b.z; wm1[7]=b.w;
  } else {
#pragma unroll
    for (int j = 0; j < 8; ++j) { wm3[j] = 0.f; wm2[j] = 0.f; wm1[j] = 0.f; }
  }
  float* xop = xo + (size_t)r0 * 2048 + ch;
  float rowmax[8];
#pragma unroll
  for (int l = 0; l < 8; ++l) {
    float cur[8];
    {
      float4 a = *(const float4*)(gb + l * 2048), b = *(const float4*)(gb + l * 2048 + 4);
      cur[0]=a.x; cur[1]=a.y; cur[2]=a.z; cur[3]=a.w; cur[4]=b.x; cur[5]=b.y; cur[6]=b.z; cur[7]=b.w;
    }
    float acc[8];
    float m = 0.f;
#pragma unroll
    for (int j = 0; j < 8; ++j) {
      float v = bias[j];
      v = fmaf(wt[0][j], wm3[j], v);
      v = fmaf(wt[1][j], wm2[j], v);
      v = fmaf(wt[2][j], wm1[j], v);
      v = fmaf(wt[3][j], cur[j], v);
      acc[j] = v;
      m = fmaxf(m, fabsf(v));
    }
    rowmax[l] = m;
    *(float4*)(xop + l * 2048) = make_float4(acc[0], acc[1], acc[2], acc[3]);
    *(float4*)(xop + l * 2048 + 4) = make_float4(acc[4], acc[5], acc[6], acc[7]);
#pragma unroll
    for (int j = 0; j < 8; ++j) { wm3[j] = wm2[j]; wm2[j] = wm1[j]; wm1[j] = cur[j]; }
  }
  __shared__ float sred[8][4];
  __shared__ float sscale[8];
#pragma unroll
  for (int l = 0; l < 8; ++l) {
    float m = rowmax[l];
#pragma unroll
    for (int off = 32; off > 0; off >>= 1) m = fmaxf(m, __shfl_xor(m, off));
    if (lane == 0) sred[l][wv] = m;
  }
  __syncthreads();
  if (tid < 8) {
    float mm = fmaxf(fmaxf(sred[tid][0], sred[tid][1]), fmaxf(sred[tid][2], sred[tid][3]));
    float s = 127.0f / fmaxf(mm, 1e-5f);
    sscale[tid] = s;
    srow[r0 + tid] = s;
  }
  __syncthreads();
  i8* qp = q + (size_t)r0 * 2048 + ch;
#pragma unroll
  for (int l = 0; l < 8; ++l) {
    float s = sscale[l];
    float4 a = *(const float4*)(xop + l * 2048);
    float4 b = *(const float4*)(xop + l * 2048 + 4);
    char4 c0q, c1q;
    c0q.x = (i8)fminf(fmaxf(rintf(a.x * s), -128.f), 127.f);
    c0q.y = (i8)fminf(fmaxf(rintf(a.y * s), -128.f), 127.f);
    c0q.z = (i8)fminf(fmaxf(rintf(a.z * s), -128.f), 127.f);
    c0q.w = (i8)fminf(fmaxf(rintf(a.w * s), -128.f), 127.f);
    c1q.x = (i8)fminf(fmaxf(rintf(b.x * s), -128.f), 127.f);
    c1q.y = (i8)fminf(fmaxf(rintf(b.y * s), -128.f), 127.f);
    c1q.z = (i8)fminf(fmaxf(rintf(b.z * s), -128.f), 127.f);
    c1q.w = (i8)fminf(fmaxf(rintf(b.w * s), -128.f), 127.f);
    *(char4*)(qp + l * 2048) = c0q;
    *(char4*)(qp + l * 2048 + 4) = c1q;
  }
}

// ---------------- GEMM2: K-split i32 partials ----------------
__global__ __launch_bounds__(256) void k_gemm2(const i8* __restrict__ q2, const i8* __restrict__ t2,
                                               int* __restrict__ ipart) {
  __shared__ i8 As[64 * LSTR];
  __shared__ i8 Bs[48 * LSTR];
  const int tid = threadIdx.x;
  const int r0 = blockIdx.x * 64;
  const int kb = blockIdx.y * 1024;
  const int lrow = tid >> 2, lk = (tid & 3) * 16;
  const int lane = tid & 63, wv = tid >> 6;
  const int fr = lane & 15, fk = (lane >> 4) * 16;
  v4i acc[3];
#pragma unroll
  for (int s = 0; s < 3; ++s) acc[s] = (v4i){0, 0, 0, 0};
  for (int ks = 0; ks < 16; ++ks) {
    const int k0 = kb + ks * 64;
    __syncthreads();
    *(v4i*)&As[lrow * LSTR + lk] = *(const v4i*)&q2[(size_t)(r0 + lrow) * 2048 + k0 + lk];
    if (tid < 192)
      *(v4i*)&Bs[(tid >> 2) * LSTR + (tid & 3) * 16] = *(const v4i*)&t2[(size_t)(tid >> 2) * 2048 + k0 + (tid & 3) * 16];
    __syncthreads();
    v4i a = *(const v4i*)&As[(wv * 16 + fr) * LSTR + fk];
#pragma unroll
    for (int s = 0; s < 3; ++s) {
      v4i b = *(const v4i*)&Bs[(s * 16 + fr) * LSTR + fk];
      acc[s] = __builtin_amdgcn_mfma_i32_16x16x64_i8(a, b, acc[s], 0, 0, 0);
    }
  }
#pragma unroll
  for (int s = 0; s < 3; ++s)
#pragma unroll
    for (int rg = 0; rg < 4; ++rg) {
      int row = wv * 16 + (lane >> 4) * 4 + rg;
      int col = s * 16 + (lane & 15);
      ipart[(size_t)blockIdx.y * 196608 + (size_t)(r0 + row) * 48 + col] = acc[s][rg];
    }
}

// ---------------- combine partials, dequant, build A_d / delta*B / C transposed ----------------
__global__ __launch_bounds__(256) void k_xform(const int* __restrict__ ip, const float* __restrict__ s2,
                                               const float* __restrict__ scales, const float* __restrict__ dbias,
                                               const float* __restrict__ logA, float* __restrict__ At,
                                               float* __restrict__ dBt, float* __restrict__ Ct) {
  int idx = blockIdx.x * 256 + threadIdx.x;
  int r = idx >> 4, n = idx & 15;
  int b = r >> 11, l = r & 2047;
  float fr = 1.0f / s2[r];
  int base = r * 48;
  float dd = (float)(ip[base + n] + ip[196608 + base + n]) * (scales[1] * fr) + dbias[n];
  float Bv = (float)(ip[base + 16 + n] + ip[196608 + base + 16 + n]) * (scales[2] * fr);
  float Cv = (float)(ip[base + 32 + n] + ip[196608 + base + 32 + n]) * (scales[3] * fr);
  int o = ((b * 16 + n) << 11) | l;
  At[o] = expf(dd * logA[n]);
  dBt[o] = dd * Bv;
  Ct[o] = Cv;
}

// ---------------- parallel scan over time per (b,n) ----------------
__global__ __launch_bounds__(256) void k_scan(const float* __restrict__ At, const float* __restrict__ dBt,
                                              const float* __restrict__ Ct, float* __restrict__ ch) {
  const int i = threadIdx.x;
  const int base = blockIdx.x << 11;
  float a[8], db[8], c[8];
  {
    const float4* p = (const float4*)(At + base + i * 8);
    float4 t0 = p[0], t1 = p[1];
    a[0]=t0.x; a[1]=t0.y; a[2]=t0.z; a[3]=t0.w; a[4]=t1.x; a[5]=t1.y; a[6]=t1.z; a[7]=t1.w;
  }
  {
    const float4* p = (const float4*)(dBt + base + i * 8);
    float4 t0 = p[0], t1 = p[1];
    db[0]=t0.x; db[1]=t0.y; db[2]=t0.z; db[3]=t0.w; db[4]=t1.x; db[5]=t1.y; db[6]=t1.z; db[7]=t1.w;
  }
  {
    const float4* p = (const float4*)(Ct + base + i * 8);
    float4 t0 = p[0], t1 = p[1];
    c[0]=t0.x; c[1]=t0.y; c[2]=t0.z; c[3]=t0.w; c[4]=t1.x; c[5]=t1.y; c[6]=t1.z; c[7]=t1.w;
  }
  float Ac = 1.f, Bc = 0.f;
#pragma unroll
  for (int j = 0; j < 8; ++j) { Bc = a[j] * Bc + db[j]; Ac *= a[j]; }
  __shared__ float sA[256], sB[256];
  sA[i] = Ac; sB[i] = Bc;
  __syncthreads();
  for (int off = 1; off < 256; off <<= 1) {
    float pA = 1.f, pB = 0.f;
    if (i >= off) { pA = sA[i - off]; pB = sB[i - off]; }
    __syncthreads();
    Bc = Ac * pB + Bc;
    Ac = Ac * pA;
    sA[i] = Ac; sB[i] = Bc;
    __syncthreads();
  }
  float h = (i > 0) ? sB[i - 1] : 0.f;
  float o[8];
#pragma unroll
  for (int j = 0; j < 8; ++j) { h = a[j] * h + db[j]; o[j] = c[j] * h; }
  float4* po = (float4*)(ch + base + i * 8);
  po[0] = make_float4(o[0], o[1], o[2], o[3]);
  po[1] = make_float4(o[4], o[5], o[6], o[7]);
}

// ---------------- y_inner scaling + act-quant, 8 rows/block ----------------
__global__ __launch_bounds__(256) void k_yq(const float* __restrict__ xin, const float* __restrict__ chb,
                                            const float* __restrict__ Dp, i8* __restrict__ q,
                                            float* __restrict__ srow) {
  const int tid = threadIdx.x;
  const int r0 = blockIdx.x * 8;
  const int b = r0 >> 11, l0 = r0 & 2047;
  const int lane = tid & 63, wv = tid >> 6;
  __shared__ float ssig[8 * 16];
  __shared__ float ssg[8];
  __shared__ float sred[8][4];
  __shared__ float sscale[8];
  if (tid < 128) {
    int n = tid >> 3, li = tid & 7;
    ssig[li * 16 + n] = chb[((size_t)(b * 16 + n) << 11) | (l0 + li)];
  }
  __syncthreads();
  if (tid < 8) {
    float s = 0.f;
    for (int n = 0; n < 16; ++n) s += ssig[tid * 16 + n];
    ssg[tid] = 1.0f / (1.0f + expf(-s));
  }
  __syncthreads();
  const int ch = tid * 8;
  float dreg[8];
  {
    float4 d0 = *(const float4*)(Dp + ch), d1 = *(const float4*)(Dp + ch + 4);
    dreg[0]=d0.x; dreg[1]=d0.y; dreg[2]=d0.z; dreg[3]=d0.w;
    dreg[4]=d1.x; dreg[5]=d1.y; dreg[6]=d1.z; dreg[7]=d1.w;
  }
  const float* xr = xin + (size_t)r0 * 2048 + ch;
  float rowmax[8];
#pragma unroll
  for (int l = 0; l < 8; ++l) {
    float sg = ssg[l];
    float4 a = *(const float4*)(xr + l * 2048);
    float4 c = *(const float4*)(xr + l * 2048 + 4);
    float m = 0.f;
    m = fmaxf(m, fabsf(a.x * (sg + dreg[0])));
    m = fmaxf(m, fabsf(a.y * (sg + dreg[1])));
    m = fmaxf(m, fabsf(a.z * (sg + dreg[2])));
    m = fmaxf(m, fabsf(a.w * (sg + dreg[3])));
    m = fmaxf(m, fabsf(c.x * (sg + dreg[4])));
    m = fmaxf(m, fabsf(c.y * (sg + dreg[5])));
    m = fmaxf(m, fabsf(c.z * (sg + dreg[6])));
    m = fmaxf(m, fabsf(c.w * (sg + dreg[7])));
    rowmax[l] = m;
  }
#pragma unroll
  for (int l = 0; l < 8; ++l) {
    float m = rowmax[l];
#pragma unroll
    for (int off = 32; off > 0; off >>= 1) m = fmaxf(m, __shfl_xor(m, off));
    if (lane == 0) sred[l][wv] = m;
  }
  __syncthreads();
  if (tid < 8) {
    float mm = fmaxf(fmaxf(sred[tid][0], sred[tid][1]), fmaxf(sred[tid][2], sred[tid][3]));
    float s = 127.0f / fmaxf(mm, 1e-5f);
    sscale[tid] = s;
    srow[r0 + tid] = s;
  }
  __syncthreads();
  i8* qp = q + (size_t)r0 * 2048 + ch;
#pragma unroll
  for (int l = 0; l < 8; ++l) {
    float s = sscale[l];
    float sg = ssg[l];
    float4 a = *(const float4*)(xr + l * 2048);
    float4 c = *(const float4*)(xr + l * 2048 + 4);
    char4 c0q, c1q;
    c0q.x = (i8)fminf(fmaxf(rintf(a.x * (sg + dreg[0]) * s), -128.f), 127.f);
    c0q.y = (i8)fminf(fmaxf(rintf(a.y * (sg + dreg[1]) * s), -128.f), 127.f);
    c0q.z = (i8)fminf(fmaxf(rintf(a.z * (sg + dreg[2]) * s), -128.f), 127.f);
    c0q.w = (i8)fminf(fmaxf(rintf(a.w * (sg + dreg[3]) * s), -128.f), 127.f);
    c1q.x = (i8)fminf(fmaxf(rintf(c.x * (sg + dreg[4]) * s), -128.f), 127.f);
    c1q.y = (i8)fminf(fmaxf(rintf(c.y * (sg + dreg[5]) * s), -128.f), 127.f);
    c1q.z = (i8)fminf(fmaxf(rintf(c.z * (sg + dreg[6]) * s), -128.f), 127.f);
    c1q.w = (i8)fminf(fmaxf(rintf(c.w * (sg + dreg[7]) * s), -128.f), 127.f);
    *(char4*)(qp + l * 2048) = c0q;
    *(char4*)(qp + l * 2048 + 4) = c1q;
  }
}

// ---------------- GEMM3: 128x128 tile, BK=64, 2-phase double-buffered pipeline ----------------
#define COMPUTE3(Ab, Bb)                                                            \
  {                                                                                 \
    v4i a[4];                                                                       \
    _Pragma("unroll") for (int m = 0; m < 4; ++m) {                                 \
      int rr = wr * 64 + m * 16 + lo;                                               \
      a[m] = *(const v4i*)&Ab[rr * 64 + ((hi ^ (rr & 3)) << 4)];                    \
    }                                                                               \
    __builtin_amdgcn_s_setprio(1);                                                  \
    _Pragma("unroll") for (int n = 0; n < 4; ++n) {                                 \
      int cc = wc * 64 + n * 16 + lo;                                               \
      v4i b = *(const v4i*)&Bb[cc * 64 + ((hi ^ (cc & 3)) << 4)];                   \
      _Pragma("unroll") for (int m = 0; m < 4; ++m)                                 \
        acc[m][n] = __builtin_amdgcn_mfma_i32_16x16x64_i8(a[m], b, acc[m][n], 0, 0, 0); \
    }                                                                               \
    __builtin_amdgcn_s_setprio(0);                                                  \
  }

__global__ __launch_bounds__(256) void k_gemm3(const i8* __restrict__ q3, const i8* __restrict__ tout,
                                               const float* __restrict__ s3, const float* __restrict__ scales,
                                               float* __restrict__ out) {
  __shared__ i8 A0[8192], A1[8192], B0[8192], B1[8192];
  __shared__ float frow[128];
  const int tid = threadIdx.x;
  const int r0 = blockIdx.x * 128, c0 = blockIdx.y * 128;
  if (tid < 128) frow[tid] = scales[4] / s3[r0 + tid];
  __syncthreads();
  const int lane = tid & 63, wv = tid >> 6;
  const int wr = wv >> 1, wc = wv & 1;
  const int lo = lane & 15, hi = lane >> 4;
  const int srw = wv * 16 + (lane >> 2);
  const int sc = lane & 3;
  v4i acc[4][4];
#pragma unroll
  for (int m = 0; m < 4; ++m)
#pragma unroll
    for (int n = 0; n < 4; ++n) acc[m][n] = (v4i){0, 0, 0, 0};

#define STAGE3(kt, Ab, Bb)                                               \
  {                                                                      \
    const int kb = (kt)*64;                                              \
    _Pragma("unroll") for (int i = 0; i < 2; ++i) {                      \
      int r = i * 64 + srw;                                              \
      int src = kb + ((sc ^ (r & 3)) << 4);                              \
      int db = i * 4096 + wv * 1024;                                     \
      gld16(q3 + (size_t)(r0 + r) * 2048 + src, Ab + db);                \
      gld16(tout + (size_t)(c0 + r) * 2048 + src, Bb + db);              \
    }                                                                    \
  }

  STAGE3(0, A0, B0);
  SYNCPIPE;
#pragma unroll
  for (int kt = 0; kt < 32; kt += 2) {
    STAGE3(kt + 1, A1, B1);
    COMPUTE3(A0, B0);
    SYNCPIPE;
    if (kt + 2 < 32) STAGE3(kt + 2, A0, B0);
    COMPUTE3(A1, B1);
    SYNCPIPE;
  }
#undef STAGE3

#pragma unroll
  for (int m = 0; m < 4; ++m)
#pragma unroll
    for (int n = 0; n < 4; ++n)
#pragma unroll
      for (int rg = 0; rg < 4; ++rg) {
        int row = wr * 64 + m * 16 + hi * 4 + rg;
        int col = wc * 64 + n * 16 + lo;
        out[(size_t)(r0 + row) * 1024 + c0 + col] = (float)acc[m][n][rg] * frow[row];
      }
}

extern "C" void kernel_launch(void* const* d_in, const int* in_sizes, int n_in,
                              void* d_out, int out_size, void* d_ws, size_t ws_size,
                              hipStream_t stream) {
  const float* x     = (const float*)d_in[0];
  const float* win   = (const float*)d_in[1];
  const float* cw    = (const float*)d_in[2];
  const float* cb    = (const float*)d_in[3];
  const float* dw    = (const float*)d_in[4];
  const float* dbias = (const float*)d_in[5];
  const float* bw    = (const float*)d_in[6];
  const float* cmw   = (const float*)d_in[7];
  const float* ow    = (const float*)d_in[8];
  const float* Dp    = (const float*)d_in[9];
  const float* logA  = (const float*)d_in[10];
  float* out = (float*)d_out;

  char* p = (char*)d_ws;
  float* gated = (float*)p;   p += (size_t)4096 * 2048 * 4;
  float* xin   = (float*)p;   p += (size_t)4096 * 2048 * 4;
  char* qx_rgn = p;           p += (size_t)4096 * 1024;
  char* tin_rgn = p;          p += (size_t)2 * 2048 * 1024;
  i8* tout = (i8*)p;          p += (size_t)1024 * 2048;
  i8* t2   = (i8*)p;          p += (size_t)48 * 2048;
  i8* q2   = (i8*)p;          p += (size_t)4096 * 2048;
  i8* q3   = (i8*)p;          p += (size_t)4096 * 2048;
  float* sx  = (float*)p;     p += (size_t)4096 * 4;
  float* s2  = (float*)p;     p += (size_t)4096 * 4;
  float* s3  = (float*)p;     p += (size_t)4096 * 4;
  float* scales = (float*)p;  p += 256;
  double* partial = (double*)p;

  i8* qx  = (i8*)qx_rgn;
  i8* tin = (i8*)tin_rgn;
  int* ipart = (int*)qx_rgn;
  float* At  = (float*)tin_rgn;
  float* dBt = At + 65536;
  float* Ct  = dBt + 65536;
  float* chb = Ct + 65536;

  k_abssum_all<<<432, 256, 0, stream>>>(win, dw, bw, cmw, ow, partial);
  k_finalize<<<1, 64, 0, stream>>>(partial, scales);
  k_wquant_all<<<6240, 256, 0, stream>>>(win, dw, bw, cmw, ow, scales, tin, t2, tout);

  k_actquant<1024><<<4096, 256, 0, stream>>>(x, qx, sx);
  k_gemm1<<<dim3(32, 16), 256, 0, stream>>>(qx, tin, sx, scales, gated);
  k_convq<<<512, 256, 0, stream>>>(gated, cw, cb, xin, q2, s2);
  k_gemm2<<<dim3(64, 2), 256, 0, stream>>>(q2, t2, ipart);
  k_xform<<<256, 256, 0, stream>>>(ipart, s2, scales, dbias, logA, At, dBt, Ct);
  k_scan<<<32, 256, 0, stream>>>(At, dBt, Ct, chb);
  k_yq<<<512, 256, 0, stream>>>(xin, chb, Dp, q3, s3);
  k_gemm3<<<dim3(32, 8), 256, 0, stream>>>(q3, tout, s3, scales, out);
}